// Round 5
// baseline (306.506 us; speedup 1.0000x reference)
//
#include <hip/hip_runtime.h>
#include <hip/hip_bf16.h>
#include <cstddef>

// Problem constants
#define B_  2
#define LV_ 1024
#define LE_ 64
#define S_TOT 1088          // LV+LE
#define DV_ 2560
#define DE_ 1920
#define H_  32
#define KVH_ 8
#define DH_ 128
#define HD_ 4096            // H*DH
#define KVD_ 1024           // KVH*DH
#define NSPL 17             // attention key splits (17 x 64 keys = 1088)

typedef short short8 __attribute__((ext_vector_type(8)));
typedef float f32x4 __attribute__((ext_vector_type(4)));

typedef __hip_bfloat16 bf16;

__device__ inline float b2f(bf16 h) { return __bfloat162float(h); }
__device__ inline bf16 f2b(float f) { return __float2bfloat16(f); }

// global -> LDS direct copy, 16B per lane (dest = wave-uniform base + lane*16)
typedef const __attribute__((address_space(1))) void* gptr_t;
typedef __attribute__((address_space(3))) void* lptr_t;
__device__ inline void gl16(const void* g, void* l) {
  __builtin_amdgcn_global_load_lds((gptr_t)g, (lptr_t)l, 16, 0, 0);
}

// ---------------- Workspace layout (byte offsets) ----------------
// hv_b   : 2048x2560 bf16 @ 0           (10,485,760)
// WkvT   : 2048x2560 bf16 @ 10,485,760  (10,485,760)
// he_b   : 128x1920 bf16  @ 20,971,520  (491,520)
// WqkvT  : 6144x1920 bf16 @ 21,463,040  (23,592,960)
// qe     : 128x4096 bf16  @ 45,056,000  (1,048,576)
// kbuf   : 2x1088x1024    @ 46,104,576  (4,456,448)
// vbuf   : 2x1088x1024    @ 50,561,024  (4,456,448)
// ao     : 128x4096 bf16  @ 59,473,920  (1,048,576)
// Aliases (stream-ordered lifetimes) — all of [0, 45,056,000) is dead after
// gemm_fused (hv_b, WkvT, he_b, WqkvT):
//  O_p   : 17x4096x128 f32 (35,651,584) @ 0
//  m_arr : 17x4096 f32 (278,528)        @ 35,651,584
//  l_arr : 17x4096 f32 (278,528)        @ 35,930,112   (end 36,208,640 < qe)
#define OFF_HVB   0ul
#define OFF_WKVT  10485760ul
#define OFF_HEB   20971520ul
#define OFF_WQKVT 21463040ul
#define OFF_QE    45056000ul
#define OFF_KBUF  46104576ul
#define OFF_VBUF  50561024ul
#define OFF_AO    59473920ul
#define OFF_OP    0ul
#define OFF_M     35651584ul
#define OFF_L     35930112ul

// ---------------- Fused RMSNorm (vlm rows 0..2047, expert rest) -> bf16 ----
__global__ __launch_bounds__(256) void rmsnorm_both(
    const float* __restrict__ xv, const float* __restrict__ wv,
    bf16* __restrict__ ov,
    const float* __restrict__ xe, const float* __restrict__ we,
    bf16* __restrict__ oe) {
  int row; const float* x; const float* w; bf16* o; int D;
  if (blockIdx.x < 2048) { row = blockIdx.x;        x = xv; w = wv; o = ov; D = DV_; }
  else                   { row = blockIdx.x - 2048; x = xe; w = we; o = oe; D = DE_; }
  const float4* x4 = (const float4*)(x + (size_t)row * D);
  const float4* w4 = (const float4*)w;
  int D4 = D >> 2;
  float ss = 0.f;
  for (int i = threadIdx.x; i < D4; i += 256) {
    float4 v = x4[i];
    ss += v.x * v.x + v.y * v.y + v.z * v.z + v.w * v.w;
  }
  __shared__ float red[256];
  red[threadIdx.x] = ss; __syncthreads();
  for (int s = 128; s > 0; s >>= 1) {
    if (threadIdx.x < s) red[threadIdx.x] += red[threadIdx.x + s];
    __syncthreads();
  }
  float inv = rsqrtf(red[0] / (float)D + 1e-6f);
  ushort4* o4 = (ushort4*)(o + (size_t)row * D);
  for (int i = threadIdx.x; i < D4; i += 256) {
    float4 v = x4[i], wv2 = w4[i];
    bf16 a = f2b(v.x * inv * wv2.x), b = f2b(v.y * inv * wv2.y);
    bf16 c = f2b(v.z * inv * wv2.z), d = f2b(v.w * inv * wv2.w);
    ushort4 ow;
    ow.x = *(ushort*)&a; ow.y = *(ushort*)&b; ow.z = *(ushort*)&c; ow.w = *(ushort*)&d;
    o4[i] = ow;
  }
}

// ---------------- 64x64 transpose-convert tile helper ----------------
__device__ inline void tile_tconv(float (*t)[65],
    const float* __restrict__ W, bf16* __restrict__ Wt,
    int K, int N, int n_off, int bx, int by) {
  int n0 = bx * 64, k0 = by * 64;
  int tid = threadIdx.x;
  int c = tid & 63, r4 = tid >> 6;
#pragma unroll 4
  for (int it = 0; it < 16; ++it) {
    int k = it * 4 + r4;
    t[k][c] = W[(size_t)(k0 + k) * N + n0 + c];
  }
  __syncthreads();
#pragma unroll 4
  for (int it = 0; it < 16; ++it) {
    int n = it * 4 + r4;
    Wt[(size_t)(n_off + n0 + n) * K + k0 + c] = f2b(t[c][n]);
  }
}

// fused: all 5 pre-GEMM weight converts in one dispatch (4160 blocks)
__global__ __launch_bounds__(256) void tconv_all(
    const float* __restrict__ Wk_vlm, const float* __restrict__ Wv_vlm,
    const float* __restrict__ Wq_exp, const float* __restrict__ Wk_exp,
    const float* __restrict__ Wv_exp,
    bf16* __restrict__ WkvT, bf16* __restrict__ WqkvT) {
  __shared__ float t[64][65];
  int id = blockIdx.x;
  if (id < 640)       tile_tconv(t, Wk_vlm, WkvT, DV_, KVD_, 0,    id % 16, id / 16);
  else if (id < 1280) { id -= 640;  tile_tconv(t, Wv_vlm, WkvT,  DV_, KVD_, 1024, id % 16, id / 16); }
  else if (id < 3200) { id -= 1280; tile_tconv(t, Wq_exp, WqkvT, DE_, HD_,  0,    id % 64, id / 64); }
  else if (id < 3680) { id -= 3200; tile_tconv(t, Wk_exp, WqkvT, DE_, KVD_, 4096, id % 16, id / 16); }
  else                { id -= 3680; tile_tconv(t, Wv_exp, WqkvT, DE_, KVD_, 5120, id % 16, id / 16); }
}

// ---------------- Fused MFMA GEMM: vlm K/V (blocks 0..511) + expert QKV ----
// 64(M) x 128(N) tile, 4 waves in 2x2 (each wave 32x64, 2x4 fragments).
// At the structural LDS-BW ceiling for this fragment geometry (R4 analysis):
// 24KB LDS reads per block-step vs 40cy/SIMD MFMA -> ~15% MfmaUtil.
__global__ __launch_bounds__(256) void gemm_fused(
    const bf16* __restrict__ hv, const bf16* __restrict__ WkvT,
    const bf16* __restrict__ he, const bf16* __restrict__ WqkvT,
    bf16* __restrict__ kbuf, bf16* __restrict__ vbuf, bf16* __restrict__ qe) {
  __shared__ ushort As[4][64][32];
  __shared__ ushort Bs[4][128][32];
  int tid = threadIdx.x;
  int lane = tid & 63, w = tid >> 6;
  int lr = lane & 15, quad = lane >> 4;
  int wmA = (w >> 1) * 32, wnB = (w & 1) * 64;

  bool expert = (blockIdx.x >= 512);
  const ushort* Ab; const ushort* Bb; int K, nsteps, m0, n0;
  if (!expert) {
    m0 = (int)(blockIdx.x >> 4) * 64; n0 = (int)(blockIdx.x & 15) * 128;
    Ab = (const ushort*)hv; Bb = (const ushort*)WkvT;
    K = DV_; nsteps = DV_ / 32;
  } else {
    int e = (int)blockIdx.x - 512;
    m0 = (e / 48) * 64; n0 = (e % 48) * 128;
    Ab = (const ushort*)he; Bb = (const ushort*)WqkvT;
    K = DE_; nsteps = DE_ / 32;
  }

  // per-lane pre-swizzled global source pointers (1 A + 2 B chunks per wave)
  int rA  = w * 16 + (lane >> 2);          // A rows: wave w covers 16 rows
  int rB0 = w * 32 + (lane >> 2);          // B rows: wave w covers 32 rows
  int rB1 = rB0 + 16;
  int sA  = (lane & 3) ^ ((rA  >> 1) & 3); // swizzled 16B slot
  int sB0 = (lane & 3) ^ ((rB0 >> 1) & 3);
  int sB1 = (lane & 3) ^ ((rB1 >> 1) & 3);
  const ushort* pa  = Ab + (size_t)(m0 + rA)  * K + sA  * 8;
  const ushort* pb0 = Bb + (size_t)(n0 + rB0) * K + sB0 * 8;
  const ushort* pb1 = Bb + (size_t)(n0 + rB1) * K + sB1 * 8;

  auto STAGE = [&](int buf, int t) {
    int k0 = t * 32;
    gl16(pa  + k0, &As[buf][w * 16][0]);
    gl16(pb0 + k0, &Bs[buf][w * 32][0]);
    gl16(pb1 + k0, &Bs[buf][w * 32 + 16][0]);
  };

  int sslot = (quad ^ ((lr >> 1) & 3)) * 8;   // fragment-read swizzled slot

  f32x4 acc[2][4] = {};

  STAGE(0, 0);
  STAGE(1, 1);
  STAGE(2, 2);
  for (int t = 0; t < nsteps; ++t) {
    int rem = nsteps - t;
    if (rem > 3) {
      STAGE((t + 3) & 3, t + 3);
      asm volatile("s_waitcnt vmcnt(9)" ::: "memory");
    } else if (rem == 3) {
      asm volatile("s_waitcnt vmcnt(6)" ::: "memory");
    } else if (rem == 2) {
      asm volatile("s_waitcnt vmcnt(3)" ::: "memory");
    } else {
      asm volatile("s_waitcnt vmcnt(0)" ::: "memory");
    }
    __builtin_amdgcn_s_barrier();

    int cur = t & 3;
    short8 af[2], bv[4];
#pragma unroll
    for (int i = 0; i < 2; ++i)
      af[i] = *(const short8*)&As[cur][wmA + i * 16 + lr][sslot];
#pragma unroll
    for (int j = 0; j < 4; ++j)
      bv[j] = *(const short8*)&Bs[cur][wnB + j * 16 + lr][sslot];
    __builtin_amdgcn_s_setprio(1);
#pragma unroll
    for (int i = 0; i < 2; ++i)
#pragma unroll
      for (int j = 0; j < 4; ++j)
        acc[i][j] = __builtin_amdgcn_mfma_f32_16x16x32_bf16(af[i], bv[j], acc[i][j], 0, 0, 0);
    __builtin_amdgcn_s_setprio(0);

    __builtin_amdgcn_s_barrier();
  }

  // ---- epilogue ----
#pragma unroll
  for (int i = 0; i < 2; ++i) {
    int mm_base = wmA + i * 16 + quad * 4;
#pragma unroll
    for (int j = 0; j < 4; ++j) {
      int gn = n0 + wnB + j * 16 + lr;
#pragma unroll
      for (int r = 0; r < 4; ++r) {
        int mm = mm_base + r;
        float v = acc[i][j][r];
        if (!expert) {
          int m = m0 + mm;
          int b = m >> 10, s = m & 1023;
          size_t row = (size_t)(b * S_TOT + s);
          if (gn < 1024) kbuf[row * KVD_ + gn] = f2b(v);
          else           vbuf[row * KVD_ + (gn - 1024)] = f2b(v);
        } else {
          int m = m0 + mm;           // 0..127
          int b = m >> 6, l = m & 63;
          if (gn < 4096) {
            qe[(size_t)m * HD_ + gn] = f2b(v);
          } else {
            size_t row = (size_t)(b * S_TOT + LV_ + l);
            if (gn < 5120) kbuf[row * KVD_ + (gn - 4096)] = f2b(v);
            else           vbuf[row * KVD_ + (gn - 5120)] = f2b(v);
          }
        }
      }
    }
  }
}

// ---------------- Output projection split-K GEMM, B = Wo f32 row-major ----
// C = ao(128xHD) * Wo(HD x 1920), K-split 16 x 256, N-tile 64.
// Accumulates into out (pre-filled with residual) via f32 atomics — no
// partial buffer, no reduce kernel.
__global__ __launch_bounds__(256) void gemm_out(
    const bf16* __restrict__ A, const float* __restrict__ W,
    float* __restrict__ out) {
  __shared__ ushort As[128][40];
  __shared__ ushort Bs[64][40];
  int tid = threadIdx.x;
  int lane = tid & 63, wid = tid >> 6;
  int wm = (wid >> 1) * 64, wn = (wid & 1) * 32;
  int n0 = blockIdx.x * 64;
  int k_beg = blockIdx.y * 256;
  int lr = lane & 15, quad = lane >> 4;

  f32x4 acc[4][2] = {};

  int ar = tid >> 2;
  int ac = (tid & 3) * 8;
  const ushort* Aptr = (const ushort*)A + (size_t)ar * HD_ + ac;
  int bn = tid & 63, kg = tid >> 6;              // B-stage: col n0+bn, rows kg*8..+7
  int bslot_w = ((kg ^ (bn & 3)) * 8);
  int brd = (quad ^ (lr & 3)) * 8;               // fragment-read slot

  for (int k0 = k_beg; k0 < k_beg + 256; k0 += 32) {
    short8 a0 = *(const short8*)(Aptr + k0);
    short8 a1 = *(const short8*)(Aptr + (size_t)64 * HD_ + k0);
    float wv[8];
#pragma unroll
    for (int j = 0; j < 8; ++j)
      wv[j] = W[(size_t)(k0 + kg * 8 + j) * DE_ + n0 + bn];
    short8 bvv;
#pragma unroll
    for (int j = 0; j < 8; ++j) { bf16 h = f2b(wv[j]); bvv[j] = *(short*)&h; }
    __syncthreads();
    *(short8*)&As[ar][ac] = a0;
    *(short8*)&As[64 + ar][ac] = a1;
    *(short8*)&Bs[bn][bslot_w] = bvv;
    __syncthreads();
    short8 af[4], bfr[2];
#pragma unroll
    for (int i = 0; i < 4; ++i)
      af[i]  = *(const short8*)&As[wm + i * 16 + lr][quad * 8];
#pragma unroll
    for (int j = 0; j < 2; ++j)
      bfr[j] = *(const short8*)&Bs[wn + j * 16 + lr][brd];
#pragma unroll
    for (int i = 0; i < 4; ++i)
#pragma unroll
      for (int j = 0; j < 2; ++j)
        acc[i][j] = __builtin_amdgcn_mfma_f32_16x16x32_bf16(af[i], bfr[j], acc[i][j], 0, 0, 0);
  }

#pragma unroll
  for (int i = 0; i < 4; ++i) {
    int m_base = wm + i * 16 + quad * 4;
#pragma unroll
    for (int j = 0; j < 2; ++j) {
      int gn = n0 + wn + j * 16 + lr;
#pragma unroll
      for (int r = 0; r < 4; ++r)
        atomicAdd(&out[(size_t)(m_base + r) * 1920 + gn], acc[i][j][r]);
    }
  }
}

// ---------------- Fused RoPE: Q (blocks 0..127) and K in-place (rest) ----------------
__global__ __launch_bounds__(256) void rope_fused(
    bf16* __restrict__ qe, bf16* __restrict__ kbuf,
    const int* __restrict__ pos_ids) {
  if (blockIdx.x < 128) {
    int row = blockIdx.x;
    int b = row >> 6, l = row & 63;
    float pos = (float)pos_ids[b * S_TOT + LV_ + l];
    bf16* qrow = qe + (size_t)row * HD_;
    for (int p = threadIdx.x; p < H_ * 64; p += 256) {
      int hh = p >> 6, i = p & 63;
      float inv_ts = expf(-9.210340371976184f * (float)i * (1.0f / 64.0f));
      float r = pos * inv_ts;
      float sn = sinf(r), cs = cosf(r);
      float x1 = b2f(qrow[hh * DH_ + i]), x2 = b2f(qrow[hh * DH_ + i + 64]);
      qrow[hh * DH_ + i]      = f2b(x1 * cs - x2 * sn);
      qrow[hh * DH_ + i + 64] = f2b(x2 * cs + x1 * sn);
    }
  } else {
    int bid = blockIdx.x - 128;
    int s = bid % S_TOT, b = bid / S_TOT;
    float pos = (float)pos_ids[b * S_TOT + s];
    size_t base = ((size_t)(b * S_TOT + s)) * KVD_;
    for (int t = threadIdx.x; t < KVH_ * 64; t += 256) {
      int kvh = t >> 6, i = t & 63;
      size_t idx = base + kvh * DH_ + i;
      float inv_ts = expf(-9.210340371976184f * (float)i * (1.0f / 64.0f));
      float r = pos * inv_ts;
      float sn = sinf(r), cs = cosf(r);
      float x1 = b2f(kbuf[idx]), x2 = b2f(kbuf[idx + 64]);
      kbuf[idx]      = f2b(x1 * cs - x2 * sn);
      kbuf[idx + 64] = f2b(x2 * cs + x1 * sn);
    }
  }
}

// ---------------- MFMA flash attention, split over keys ----------------
// grid: 1088 = (b,h) x 17 splits; each block handles exactly 64 keys.
// (R5: 17x64 replaces 9x128 — halves block length so the 256-CU makespan is
// ~2.1 rounds instead of 3; single-tile blocks drop the online rescale.)
// Writes unnormalized partial O (f32) + split-local m,l per q row.
__global__ __launch_bounds__(256) void attn_part(
    const bf16* __restrict__ qe, const bf16* __restrict__ kbuf,
    const bf16* __restrict__ vbuf,
    float* __restrict__ O_p, float* __restrict__ m_arr,
    float* __restrict__ l_arr) {
  int bh = blockIdx.x & 63;              // (b<<5)|h
  int split = blockIdx.x >> 6;           // 0..16
  int h = bh & 31, b = bh >> 5;
  int kvh = h >> 2;                      // G=4
  int tid = threadIdx.x;
  int lane = tid & 63, wid = tid >> 6;
  int lr = lane & 15, quad = lane >> 4;

  __shared__ ushort Ks[64][152];
  __shared__ ushort vTs[128][72];
  __shared__ ushort sc[4][16][72];

  // Q A-fragments: lane holds Q[m=lr][k=quad*8+j], 4 k-steps of 32
  short8 qf[4];
  {
    const ushort* qptr = (const ushort*)qe +
        ((size_t)(b * LE_ + wid * 16 + lr)) * HD_ + h * DH_ + quad * 8;
#pragma unroll
    for (int ks = 0; ks < 4; ++ks) qf[ks] = *(const short8*)(qptr + ks * 32);
  }

  f32x4 Of[8] = {};                      // O C-frags: row=quad*4+r, col=lr+16*nt
  float m_i[4], l_i[4];

  const float scale = 0.08838834764831845f;   // 128^-0.5
  int key0 = split * 64;

  // ---- stage K chunk (64 keys x 128 d), row-major ----
  {
    int dg = tid & 15, kq = tid >> 4;       // 16 keys per iter
#pragma unroll
    for (int it = 0; it < 4; ++it) {
      int key = it * 16 + kq;
      short8 v = *(const short8*)((const ushort*)kbuf +
          ((size_t)(b * S_TOT + key0 + key) * KVH_ + kvh) * DH_ + dg * 8);
      *(short8*)&Ks[key][dg * 8] = v;
    }
  }
  // ---- stage V chunk transposed: vTs[d][key] ----
  {
    int key = tid & 63, dgrp = tid >> 6;
    const ushort* vp = (const ushort*)vbuf +
        ((size_t)(b * S_TOT + key0 + key) * KVH_ + kvh) * DH_ + dgrp * 32;
    short8 vv[4];
#pragma unroll
    for (int q8 = 0; q8 < 4; ++q8) vv[q8] = *(const short8*)(vp + q8 * 8);
#pragma unroll
    for (int q8 = 0; q8 < 4; ++q8)
#pragma unroll
      for (int j = 0; j < 8; ++j)
        vTs[dgrp * 32 + q8 * 8 + j][key] = (ushort)vv[q8][j];
  }
  __syncthreads();

  // ---- QK^T: S (16q x 64k) in 4 C-frags ----
  f32x4 Sf[4] = {};
#pragma unroll
  for (int kt = 0; kt < 4; ++kt)
#pragma unroll
    for (int ks = 0; ks < 4; ++ks) {
      short8 kf = *(const short8*)&Ks[kt * 16 + lr][quad * 8 + ks * 32];
      Sf[kt] = __builtin_amdgcn_mfma_f32_16x16x32_bf16(qf[ks], kf, Sf[kt], 0, 0, 0);
    }

  // ---- softmax numerator (single tile: no rescale needed) ----
#pragma unroll
  for (int kt = 0; kt < 4; ++kt) Sf[kt] *= scale;
#pragma unroll
  for (int r = 0; r < 4; ++r) {
    float mx = fmaxf(fmaxf(Sf[0][r], Sf[1][r]), fmaxf(Sf[2][r], Sf[3][r]));
#pragma unroll
    for (int msk = 1; msk < 16; msk <<= 1) mx = fmaxf(mx, __shfl_xor(mx, msk));
    m_i[r] = mx;
    float ls = 0.f;
#pragma unroll
    for (int kt = 0; kt < 4; ++kt) {
      float p = __expf(Sf[kt][r] - mx);
      Sf[kt][r] = p;
      ls += p;
    }
    l_i[r] = ls;
#pragma unroll
    for (int kt = 0; kt < 4; ++kt) {
      bf16 t = f2b(Sf[kt][r]);
      sc[wid][quad * 4 + r][kt * 16 + lr] = *(ushort*)&t;
    }
  }

  // ---- PV: O = P (16x64) * V (64x128) ----
#pragma unroll
  for (int ks = 0; ks < 2; ++ks) {
    short8 pf = *(const short8*)&sc[wid][lr][quad * 8 + ks * 32];
#pragma unroll
    for (int nt = 0; nt < 8; ++nt) {
      short8 vf = *(const short8*)&vTs[nt * 16 + lr][quad * 8 + ks * 32];
      Of[nt] = __builtin_amdgcn_mfma_f32_16x16x32_bf16(pf, vf, Of[nt], 0, 0, 0);
    }
  }

  // ---- finalize l: per-lane l_i covers only cols {lr,16+lr,32+lr,48+lr};
  //      sum across the 16-lane lr group for the true row sum ----
  float l_row[4];
#pragma unroll
  for (int r = 0; r < 4; ++r) {
    float l = l_i[r];
#pragma unroll
    for (int msk = 1; msk < 16; msk <<= 1) l += __shfl_xor(l, msk);
    l_row[r] = l;
  }

  // ---- write partials: O_p[(split*4096 + row)*128 + d], row=(b*32+h)*64+q ----
  size_t rbase = (size_t)split * 4096 + (size_t)bh * 64;
#pragma unroll
  for (int nt = 0; nt < 8; ++nt)
#pragma unroll
    for (int r = 0; r < 4; ++r) {
      int q = wid * 16 + quad * 4 + r;
      O_p[(rbase + q) * 128 + nt * 16 + lr] = Of[nt][r];
    }
  if (lr == 0) {
#pragma unroll
    for (int r = 0; r < 4; ++r) {
      int q = wid * 16 + quad * 4 + r;
      m_arr[rbase + q] = m_i[r];
      l_arr[rbase + q] = l_row[r];
    }
  }
}

// ---------------- Combine attention splits -> ao (bf16) ----------------
__global__ __launch_bounds__(256) void attn_combine(
    const float* __restrict__ O_p, const float* __restrict__ m_arr,
    const float* __restrict__ l_arr, bf16* __restrict__ ao) {
  int t = blockIdx.x * 256 + threadIdx.x;    // over 4096*128
  int d = t & 127, row = t >> 7;             // row=(b*32+h)*64+q
  float m_g = -1e30f;
#pragma unroll
  for (int s = 0; s < NSPL; ++s) m_g = fmaxf(m_g, m_arr[s * 4096 + row]);
  float denom = 0.f, acc = 0.f;
#pragma unroll
  for (int s = 0; s < NSPL; ++s) {
    float w = __expf(m_arr[s * 4096 + row] - m_g);
    denom += w * l_arr[s * 4096 + row];
    acc   += w * O_p[((size_t)s * 4096 + row) * 128 + d];
  }
  int b = row >> 11, h = (row >> 6) & 31, q = row & 63;
  bf16 o = f2b(acc / denom);
  ((ushort*)ao)[((size_t)(b * 64 + q) * 32 + h) * 128 + d] = *(ushort*)&o;
}

extern "C" void kernel_launch(void* const* d_in, const int* in_sizes, int n_in,
                              void* d_out, int out_size, void* d_ws, size_t ws_size,
                              hipStream_t stream) {
  const float* vlm      = (const float*)d_in[0];
  const float* expe     = (const float*)d_in[1];
  const int*   pos      = (const int*)d_in[2];
  // d_in[3] attention_mask: all-True -> unmasked softmax equivalent
  const float* w_ln_vlm = (const float*)d_in[4];
  // d_in[5] Wq_vlm unused (vlm queries don't affect expert outputs)
  const float* Wk_vlm   = (const float*)d_in[6];
  const float* Wv_vlm   = (const float*)d_in[7];
  // d_in[8] Wo_vlm unused
  const float* w_ln_exp = (const float*)d_in[9];
  const float* Wq_exp   = (const float*)d_in[10];
  const float* Wk_exp   = (const float*)d_in[11];
  const float* Wv_exp   = (const float*)d_in[12];
  const float* Wo_exp   = (const float*)d_in[13];
  float* out = (float*)d_out;
  char* ws = (char*)d_ws;

  bf16* hv_b  = (bf16*)(ws + OFF_HVB);
  bf16* WkvT  = (bf16*)(ws + OFF_WKVT);
  bf16* he_b  = (bf16*)(ws + OFF_HEB);
  bf16* WqkvT = (bf16*)(ws + OFF_WQKVT);
  bf16* qe    = (bf16*)(ws + OFF_QE);
  bf16* kbuf  = (bf16*)(ws + OFF_KBUF);
  bf16* vbuf  = (bf16*)(ws + OFF_VBUF);
  bf16* ao    = (bf16*)(ws + OFF_AO);
  float* O_p   = (float*)(ws + OFF_OP);
  float* m_arr = (float*)(ws + OFF_M);
  float* l_arr = (float*)(ws + OFF_L);

  // 0) pre-fill output with residual (D2D, graph-safe)
  hipMemcpyAsync(out, expe, (size_t)B_ * LE_ * DE_ * sizeof(float),
                 hipMemcpyDeviceToDevice, stream);

  // 1) RMSNorm (vlm + expert) -> bf16, one dispatch
  rmsnorm_both<<<B_ * LV_ + B_ * LE_, 256, 0, stream>>>(
      vlm, w_ln_vlm, hv_b, expe, w_ln_exp, he_b);

  // 2) all pre-GEMM weight transpose-converts, one dispatch
  tconv_all<<<4160, 256, 0, stream>>>(Wk_vlm, Wv_vlm, Wq_exp, Wk_exp, Wv_exp,
                                      WkvT, WqkvT);

  // 3) fused GEMM: blocks 0..511 vlm K/V (M=2048,N=2048,K=2560, 64x128 tiles),
  //    blocks 512..607 expert QKV (M=128,N=6144,K=1920), direct bf16 epilogue
  gemm_fused<<<608, 256, 0, stream>>>(hv_b, WkvT, he_b, WqkvT, kbuf, vbuf, qe);

  // 4) RoPE (Q + K in-place), one dispatch
  rope_fused<<<128 + B_ * S_TOT, 256, 0, stream>>>(qe, kbuf, pos);

  // 5) flash attention, 17 key-splits (64 keys each) -> partials, then combine
  attn_part<<<64 * NSPL, 256, 0, stream>>>(qe, kbuf, vbuf, O_p, m_arr, l_arr);
  attn_combine<<<4096 * 128 / 256, 256, 0, stream>>>(O_p, m_arr, l_arr, ao);

  // 6) output projection, split-K, atomic f32 accumulate into out (+residual)
  gemm_out<<<dim3(30, 16), 256, 0, stream>>>(ao, Wo_exp, out);
}

// Round 6
// 304.449 us; speedup vs baseline: 1.0068x; 1.0068x over previous
//
#include <hip/hip_runtime.h>
#include <hip/hip_bf16.h>
#include <cstddef>

// Problem constants
#define B_  2
#define LV_ 1024
#define LE_ 64
#define S_TOT 1088          // LV+LE
#define DV_ 2560
#define DE_ 1920
#define H_  32
#define KVH_ 8
#define DH_ 128
#define HD_ 4096            // H*DH
#define KVD_ 1024           // KVH*DH
#define NSPL 9              // attention key splits (8x128 + 1x64)

typedef short short8 __attribute__((ext_vector_type(8)));
typedef float f32x4 __attribute__((ext_vector_type(4)));

typedef __hip_bfloat16 bf16;

__device__ inline float b2f(bf16 h) { return __bfloat162float(h); }
__device__ inline bf16 f2b(float f) { return __float2bfloat16(f); }

// global -> LDS direct copy, 16B per lane (dest = wave-uniform base + lane*16)
typedef const __attribute__((address_space(1))) void* gptr_t;
typedef __attribute__((address_space(3))) void* lptr_t;
__device__ inline void gl16(const void* g, void* l) {
  __builtin_amdgcn_global_load_lds((gptr_t)g, (lptr_t)l, 16, 0, 0);
}

// ---------------- Workspace layout (byte offsets) ----------------
// hv_b   : 2048x2560 bf16 @ 0           (10,485,760)
// WkvT   : 2048x2560 bf16 @ 10,485,760  (10,485,760)
// he_b   : 128x1920 bf16  @ 20,971,520  (491,520)
// WqkvT  : 6144x1920 bf16 @ 21,463,040  (23,592,960)
// qe     : 128x4096 bf16  @ 45,056,000  (1,048,576)
// kbuf   : 2x1088x1024    @ 46,104,576  (4,456,448)
// vbuf   : 2x1088x1024    @ 50,561,024  (4,456,448)
// ao     : 128x4096 bf16  @ 59,473,920  (1,048,576)
// Aliases — all of [0, 45,056,000) is dead after gemm_fused:
//  O_p   : 9x4096x128 f32 (18,874,368) @ 0
//  m_arr : 9x4096 f32 (147,456)        @ 18,874,368
//  l_arr : 9x4096 f32 (147,456)        @ 19,021,824   (end 19,169,280 < qe)
#define OFF_HVB   0ul
#define OFF_WKVT  10485760ul
#define OFF_HEB   20971520ul
#define OFF_WQKVT 21463040ul
#define OFF_QE    45056000ul
#define OFF_KBUF  46104576ul
#define OFF_VBUF  50561024ul
#define OFF_AO    59473920ul
#define OFF_OP    0ul
#define OFF_M     18874368ul
#define OFF_L     19021824ul

// ---------------- Fused RMSNorm (vlm rows 0..2047, expert rest) -> bf16 ----
__global__ __launch_bounds__(256) void rmsnorm_both(
    const float* __restrict__ xv, const float* __restrict__ wv,
    bf16* __restrict__ ov,
    const float* __restrict__ xe, const float* __restrict__ we,
    bf16* __restrict__ oe) {
  int row; const float* x; const float* w; bf16* o; int D;
  if (blockIdx.x < 2048) { row = blockIdx.x;        x = xv; w = wv; o = ov; D = DV_; }
  else                   { row = blockIdx.x - 2048; x = xe; w = we; o = oe; D = DE_; }
  const float4* x4 = (const float4*)(x + (size_t)row * D);
  const float4* w4 = (const float4*)w;
  int D4 = D >> 2;
  float ss = 0.f;
  for (int i = threadIdx.x; i < D4; i += 256) {
    float4 v = x4[i];
    ss += v.x * v.x + v.y * v.y + v.z * v.z + v.w * v.w;
  }
  __shared__ float red[256];
  red[threadIdx.x] = ss; __syncthreads();
  for (int s = 128; s > 0; s >>= 1) {
    if (threadIdx.x < s) red[threadIdx.x] += red[threadIdx.x + s];
    __syncthreads();
  }
  float inv = rsqrtf(red[0] / (float)D + 1e-6f);
  ushort4* o4 = (ushort4*)(o + (size_t)row * D);
  for (int i = threadIdx.x; i < D4; i += 256) {
    float4 v = x4[i], wv2 = w4[i];
    bf16 a = f2b(v.x * inv * wv2.x), b = f2b(v.y * inv * wv2.y);
    bf16 c = f2b(v.z * inv * wv2.z), d = f2b(v.w * inv * wv2.w);
    ushort4 ow;
    ow.x = *(ushort*)&a; ow.y = *(ushort*)&b; ow.z = *(ushort*)&c; ow.w = *(ushort*)&d;
    o4[i] = ow;
  }
}

// ---------------- 64x64 transpose-convert tile helper ----------------
__device__ inline void tile_tconv(float (*t)[65],
    const float* __restrict__ W, bf16* __restrict__ Wt,
    int K, int N, int n_off, int bx, int by) {
  int n0 = bx * 64, k0 = by * 64;
  int tid = threadIdx.x;
  int c = tid & 63, r4 = tid >> 6;
#pragma unroll 4
  for (int it = 0; it < 16; ++it) {
    int k = it * 4 + r4;
    t[k][c] = W[(size_t)(k0 + k) * N + n0 + c];
  }
  __syncthreads();
#pragma unroll 4
  for (int it = 0; it < 16; ++it) {
    int n = it * 4 + r4;
    Wt[(size_t)(n_off + n0 + n) * K + k0 + c] = f2b(t[c][n]);
  }
}

// fused: all 5 pre-GEMM weight converts in one dispatch (4160 blocks)
__global__ __launch_bounds__(256) void tconv_all(
    const float* __restrict__ Wk_vlm, const float* __restrict__ Wv_vlm,
    const float* __restrict__ Wq_exp, const float* __restrict__ Wk_exp,
    const float* __restrict__ Wv_exp,
    bf16* __restrict__ WkvT, bf16* __restrict__ WqkvT) {
  __shared__ float t[64][65];
  int id = blockIdx.x;
  if (id < 640)       tile_tconv(t, Wk_vlm, WkvT, DV_, KVD_, 0,    id % 16, id / 16);
  else if (id < 1280) { id -= 640;  tile_tconv(t, Wv_vlm, WkvT,  DV_, KVD_, 1024, id % 16, id / 16); }
  else if (id < 3200) { id -= 1280; tile_tconv(t, Wq_exp, WqkvT, DE_, HD_,  0,    id % 64, id / 64); }
  else if (id < 3680) { id -= 3200; tile_tconv(t, Wk_exp, WqkvT, DE_, KVD_, 4096, id % 16, id / 16); }
  else                { id -= 3680; tile_tconv(t, Wv_exp, WqkvT, DE_, KVD_, 5120, id % 16, id / 16); }
}

// ---------------- Fused MFMA GEMM: vlm K/V (blocks 0..1023) + expert QKV ----
// 64x64 tile, 4 waves (2x2 of 32x32, 2x2 fragments each). Grid 1216
// (~4.75 blocks/CU, 6 fit in 24KB LDS): per-step fixed overhead (barriers,
// vmcnt, ds_read issue) hides behind ~19 resident waves/CU of MFMA (R6
// theory: occupancy, not LDS BW, was the 15%-MfmaUtil wall; R4's 11->21%
// occupancy bump moved util commensurately).
// Staging: gl16 width-16, XOR slot swizzle on global source AND fragment
// read (0 bank conflicts, verified R2-R5). 1 A + 1 B gl16 per wave per step;
// 3-deep pipeline, steady vmcnt(4).
__global__ __launch_bounds__(256) void gemm_fused(
    const bf16* __restrict__ hv, const bf16* __restrict__ WkvT,
    const bf16* __restrict__ he, const bf16* __restrict__ WqkvT,
    bf16* __restrict__ kbuf, bf16* __restrict__ vbuf, bf16* __restrict__ qe) {
  __shared__ ushort As[3][64][32];
  __shared__ ushort Bs[3][64][32];
  int tid = threadIdx.x;
  int lane = tid & 63, w = tid >> 6;
  int lr = lane & 15, quad = lane >> 4;
  int wm = (w >> 1) * 32, wn = (w & 1) * 32;

  bool expert = (blockIdx.x >= 1024);
  const ushort* Ab; const ushort* Bb; int K, nsteps, m0, n0;
  if (!expert) {
    m0 = (int)(blockIdx.x >> 5) * 64; n0 = (int)(blockIdx.x & 31) * 64;
    Ab = (const ushort*)hv; Bb = (const ushort*)WkvT;
    K = DV_; nsteps = DV_ / 32;
  } else {
    int e = (int)blockIdx.x - 1024;
    m0 = (e / 96) * 64; n0 = (e % 96) * 64;
    Ab = (const ushort*)he; Bb = (const ushort*)WqkvT;
    K = DE_; nsteps = DE_ / 32;
  }

  // per-lane pre-swizzled global source pointers (1 A + 1 B gl16 per wave)
  int rr = w * 16 + (lane >> 2);           // row covered by this lane
  int ss = (lane & 3) ^ ((rr >> 1) & 3);   // swizzled 16B slot
  const ushort* pa = Ab + (size_t)(m0 + rr) * K + ss * 8;
  const ushort* pb = Bb + (size_t)(n0 + rr) * K + ss * 8;

  auto STAGE = [&](int buf, int t) {
    int k0 = t * 32;
    gl16(pa + k0, &As[buf][w * 16][0]);
    gl16(pb + k0, &Bs[buf][w * 16][0]);
  };

  int sslot = (quad ^ ((lr >> 1) & 3)) * 8;   // fragment-read swizzled slot

  f32x4 acc[2][2] = {};

  STAGE(0, 0);
  STAGE(1, 1);
  int cur = 0, nxt = 2;
  for (int t = 0; t < nsteps; ++t) {
    int rem = nsteps - t;
    if (rem > 2) {
      STAGE(nxt, t + 2);
      asm volatile("s_waitcnt vmcnt(4)" ::: "memory");
    } else if (rem == 2) {
      asm volatile("s_waitcnt vmcnt(2)" ::: "memory");
    } else {
      asm volatile("s_waitcnt vmcnt(0)" ::: "memory");
    }
    __builtin_amdgcn_s_barrier();

    short8 af[2], bv[2];
#pragma unroll
    for (int i = 0; i < 2; ++i) {
      af[i] = *(const short8*)&As[cur][wm + i * 16 + lr][sslot];
      bv[i] = *(const short8*)&Bs[cur][wn + i * 16 + lr][sslot];
    }
    __builtin_amdgcn_s_setprio(1);
#pragma unroll
    for (int i = 0; i < 2; ++i)
#pragma unroll
      for (int j = 0; j < 2; ++j)
        acc[i][j] = __builtin_amdgcn_mfma_f32_16x16x32_bf16(af[i], bv[j], acc[i][j], 0, 0, 0);
    __builtin_amdgcn_s_setprio(0);

    __builtin_amdgcn_s_barrier();
    cur = (cur == 2) ? 0 : cur + 1;
    nxt = (nxt == 2) ? 0 : nxt + 1;
  }

  // ---- epilogue ----
#pragma unroll
  for (int i = 0; i < 2; ++i) {
    int mm_base = wm + i * 16 + quad * 4;
#pragma unroll
    for (int j = 0; j < 2; ++j) {
      int gn = n0 + wn + j * 16 + lr;
#pragma unroll
      for (int r = 0; r < 4; ++r) {
        int mm = mm_base + r;
        float v = acc[i][j][r];
        if (!expert) {
          int m = m0 + mm;
          int b = m >> 10, s = m & 1023;
          size_t row = (size_t)(b * S_TOT + s);
          if (gn < 1024) kbuf[row * KVD_ + gn] = f2b(v);
          else           vbuf[row * KVD_ + (gn - 1024)] = f2b(v);
        } else {
          int m = m0 + mm;           // 0..127
          int b = m >> 6, l = m & 63;
          if (gn < 4096) {
            qe[(size_t)m * HD_ + gn] = f2b(v);
          } else {
            size_t row = (size_t)(b * S_TOT + LV_ + l);
            if (gn < 5120) kbuf[row * KVD_ + (gn - 4096)] = f2b(v);
            else           vbuf[row * KVD_ + (gn - 5120)] = f2b(v);
          }
        }
      }
    }
  }
}

// ---------------- Output projection split-K GEMM, B = Wo f32 row-major ----
// C = ao(128xHD) * Wo(HD x 1920), K-split 16 x 256, N-tile 64.
// Accumulates into out (pre-filled with residual) via f32 atomics.
__global__ __launch_bounds__(256) void gemm_out(
    const bf16* __restrict__ A, const float* __restrict__ W,
    float* __restrict__ out) {
  __shared__ ushort As[128][40];
  __shared__ ushort Bs[64][40];
  int tid = threadIdx.x;
  int lane = tid & 63, wid = tid >> 6;
  int wm = (wid >> 1) * 64, wn = (wid & 1) * 32;
  int n0 = blockIdx.x * 64;
  int k_beg = blockIdx.y * 256;
  int lr = lane & 15, quad = lane >> 4;

  f32x4 acc[4][2] = {};

  int ar = tid >> 2;
  int ac = (tid & 3) * 8;
  const ushort* Aptr = (const ushort*)A + (size_t)ar * HD_ + ac;
  int bn = tid & 63, kg = tid >> 6;              // B-stage: col n0+bn, rows kg*8..+7
  int bslot_w = ((kg ^ (bn & 3)) * 8);
  int brd = (quad ^ (lr & 3)) * 8;               // fragment-read slot

  for (int k0 = k_beg; k0 < k_beg + 256; k0 += 32) {
    short8 a0 = *(const short8*)(Aptr + k0);
    short8 a1 = *(const short8*)(Aptr + (size_t)64 * HD_ + k0);
    float wv[8];
#pragma unroll
    for (int j = 0; j < 8; ++j)
      wv[j] = W[(size_t)(k0 + kg * 8 + j) * DE_ + n0 + bn];
    short8 bvv;
#pragma unroll
    for (int j = 0; j < 8; ++j) { bf16 h = f2b(wv[j]); bvv[j] = *(short*)&h; }
    __syncthreads();
    *(short8*)&As[ar][ac] = a0;
    *(short8*)&As[64 + ar][ac] = a1;
    *(short8*)&Bs[bn][bslot_w] = bvv;
    __syncthreads();
    short8 af[4], bfr[2];
#pragma unroll
    for (int i = 0; i < 4; ++i)
      af[i]  = *(const short8*)&As[wm + i * 16 + lr][quad * 8];
#pragma unroll
    for (int j = 0; j < 2; ++j)
      bfr[j] = *(const short8*)&Bs[wn + j * 16 + lr][brd];
#pragma unroll
    for (int i = 0; i < 4; ++i)
#pragma unroll
      for (int j = 0; j < 2; ++j)
        acc[i][j] = __builtin_amdgcn_mfma_f32_16x16x32_bf16(af[i], bfr[j], acc[i][j], 0, 0, 0);
  }

#pragma unroll
  for (int i = 0; i < 4; ++i) {
    int m_base = wm + i * 16 + quad * 4;
#pragma unroll
    for (int j = 0; j < 2; ++j) {
      int gn = n0 + wn + j * 16 + lr;
#pragma unroll
      for (int r = 0; r < 4; ++r)
        atomicAdd(&out[(size_t)(m_base + r) * 1920 + gn], acc[i][j][r]);
    }
  }
}

// ---------------- Fused RoPE: Q (blocks 0..127) and K in-place (rest) ----------------
__global__ __launch_bounds__(256) void rope_fused(
    bf16* __restrict__ qe, bf16* __restrict__ kbuf,
    const int* __restrict__ pos_ids) {
  if (blockIdx.x < 128) {
    int row = blockIdx.x;
    int b = row >> 6, l = row & 63;
    float pos = (float)pos_ids[b * S_TOT + LV_ + l];
    bf16* qrow = qe + (size_t)row * HD_;
    for (int p = threadIdx.x; p < H_ * 64; p += 256) {
      int hh = p >> 6, i = p & 63;
      float inv_ts = expf(-9.210340371976184f * (float)i * (1.0f / 64.0f));
      float r = pos * inv_ts;
      float sn = sinf(r), cs = cosf(r);
      float x1 = b2f(qrow[hh * DH_ + i]), x2 = b2f(qrow[hh * DH_ + i + 64]);
      qrow[hh * DH_ + i]      = f2b(x1 * cs - x2 * sn);
      qrow[hh * DH_ + i + 64] = f2b(x2 * cs + x1 * sn);
    }
  } else {
    int bid = blockIdx.x - 128;
    int s = bid % S_TOT, b = bid / S_TOT;
    float pos = (float)pos_ids[b * S_TOT + s];
    size_t base = ((size_t)(b * S_TOT + s)) * KVD_;
    for (int t = threadIdx.x; t < KVH_ * 64; t += 256) {
      int kvh = t >> 6, i = t & 63;
      size_t idx = base + kvh * DH_ + i;
      float inv_ts = expf(-9.210340371976184f * (float)i * (1.0f / 64.0f));
      float r = pos * inv_ts;
      float sn = sinf(r), cs = cosf(r);
      float x1 = b2f(kbuf[idx]), x2 = b2f(kbuf[idx + 64]);
      kbuf[idx]      = f2b(x1 * cs - x2 * sn);
      kbuf[idx + 64] = f2b(x2 * cs + x1 * sn);
    }
  }
}

// ---------------- MFMA flash attention, split over keys ----------------
// grid: 576 = (b,h) x 9 splits. Splits 0..7: 128 keys (2 chunks); split 8: 64.
// (R6: reverted from 17x64 — the extra O_p traffic cost more than the
// makespan win.) Writes unnormalized partial O (f32) + chunk-local m,l.
__global__ __launch_bounds__(256) void attn_part(
    const bf16* __restrict__ qe, const bf16* __restrict__ kbuf,
    const bf16* __restrict__ vbuf,
    float* __restrict__ O_p, float* __restrict__ m_arr,
    float* __restrict__ l_arr) {
  int bh = blockIdx.x & 63;              // (b<<5)|h
  int split = blockIdx.x >> 6;           // 0..8
  int h = bh & 31, b = bh >> 5;
  int kvh = h >> 2;                      // G=4
  int tid = threadIdx.x;
  int lane = tid & 63, wid = tid >> 6;
  int lr = lane & 15, quad = lane >> 4;

  __shared__ ushort Ks[64][152];
  __shared__ ushort vTs[128][72];
  __shared__ ushort sc[4][16][72];

  // Q A-fragments: lane holds Q[m=lr][k=quad*8+j], 4 k-steps of 32
  short8 qf[4];
  {
    const ushort* qptr = (const ushort*)qe +
        ((size_t)(b * LE_ + wid * 16 + lr)) * HD_ + h * DH_ + quad * 8;
#pragma unroll
    for (int ks = 0; ks < 4; ++ks) qf[ks] = *(const short8*)(qptr + ks * 32);
  }

  f32x4 Of[8] = {};                      // O C-frags: row=quad*4+r, col=lr+16*nt
  float m_i[4], l_i[4];
#pragma unroll
  for (int r = 0; r < 4; ++r) { m_i[r] = -1e30f; l_i[r] = 0.f; }

  const float scale = 0.08838834764831845f;   // 128^-0.5
  int nch = (split == 8) ? 1 : 2;

  for (int c = 0; c < nch; ++c) {
    int key0 = split * 128 + c * 64;
    __syncthreads();
    // ---- stage K chunk (64 keys x 128 d), row-major ----
    {
      int dg = tid & 15, kq = tid >> 4;       // 16 keys per iter
#pragma unroll
      for (int it = 0; it < 4; ++it) {
        int key = it * 16 + kq;
        short8 v = *(const short8*)((const ushort*)kbuf +
            ((size_t)(b * S_TOT + key0 + key) * KVH_ + kvh) * DH_ + dg * 8);
        *(short8*)&Ks[key][dg * 8] = v;
      }
    }
    // ---- stage V chunk transposed: vTs[d][key] ----
    {
      int key = tid & 63, dgrp = tid >> 6;
      const ushort* vp = (const ushort*)vbuf +
          ((size_t)(b * S_TOT + key0 + key) * KVH_ + kvh) * DH_ + dgrp * 32;
      short8 vv[4];
#pragma unroll
      for (int q8 = 0; q8 < 4; ++q8) vv[q8] = *(const short8*)(vp + q8 * 8);
#pragma unroll
      for (int q8 = 0; q8 < 4; ++q8)
#pragma unroll
        for (int j = 0; j < 8; ++j)
          vTs[dgrp * 32 + q8 * 8 + j][key] = (ushort)vv[q8][j];
    }
    __syncthreads();

    // ---- QK^T: S (16q x 64k) in 4 C-frags ----
    f32x4 Sf[4] = {};
#pragma unroll
    for (int kt = 0; kt < 4; ++kt)
#pragma unroll
      for (int ks = 0; ks < 4; ++ks) {
        short8 kf = *(const short8*)&Ks[kt * 16 + lr][quad * 8 + ks * 32];
        Sf[kt] = __builtin_amdgcn_mfma_f32_16x16x32_bf16(qf[ks], kf, Sf[kt], 0, 0, 0);
      }

    // ---- online softmax (rows r -> q = quad*4+r) ----
#pragma unroll
    for (int kt = 0; kt < 4; ++kt) Sf[kt] *= scale;
#pragma unroll
    for (int r = 0; r < 4; ++r) {
      float mx = fmaxf(fmaxf(Sf[0][r], Sf[1][r]), fmaxf(Sf[2][r], Sf[3][r]));
#pragma unroll
      for (int msk = 1; msk < 16; msk <<= 1) mx = fmaxf(mx, __shfl_xor(mx, msk));
      float mn = fmaxf(m_i[r], mx);
      float alpha = __expf(m_i[r] - mn);
      m_i[r] = mn;
      float ls = 0.f;
#pragma unroll
      for (int kt = 0; kt < 4; ++kt) {
        float p = __expf(Sf[kt][r] - mn);
        Sf[kt][r] = p;
        ls += p;
      }
      l_i[r] = l_i[r] * alpha + ls;
#pragma unroll
      for (int nt = 0; nt < 8; ++nt) Of[nt][r] *= alpha;
#pragma unroll
      for (int kt = 0; kt < 4; ++kt) {
        bf16 t = f2b(Sf[kt][r]);
        sc[wid][quad * 4 + r][kt * 16 + lr] = *(ushort*)&t;
      }
    }

    // ---- PV: O += P (16x64) * V (64x128) ----
#pragma unroll
    for (int ks = 0; ks < 2; ++ks) {
      short8 pf = *(const short8*)&sc[wid][lr][quad * 8 + ks * 32];
#pragma unroll
      for (int nt = 0; nt < 8; ++nt) {
        short8 vf = *(const short8*)&vTs[nt * 16 + lr][quad * 8 + ks * 32];
        Of[nt] = __builtin_amdgcn_mfma_f32_16x16x32_bf16(pf, vf, Of[nt], 0, 0, 0);
      }
    }
  }

  // ---- finalize l: sum across the 16-lane lr group for the true row sum ----
  float l_row[4];
#pragma unroll
  for (int r = 0; r < 4; ++r) {
    float l = l_i[r];
#pragma unroll
    for (int msk = 1; msk < 16; msk <<= 1) l += __shfl_xor(l, msk);
    l_row[r] = l;
  }

  // ---- write partials: O_p[(split*4096 + row)*128 + d], row=(b*32+h)*64+q ----
  size_t rbase = (size_t)split * 4096 + (size_t)bh * 64;
#pragma unroll
  for (int nt = 0; nt < 8; ++nt)
#pragma unroll
    for (int r = 0; r < 4; ++r) {
      int q = wid * 16 + quad * 4 + r;
      O_p[(rbase + q) * 128 + nt * 16 + lr] = Of[nt][r];
    }
  if (lr == 0) {
#pragma unroll
    for (int r = 0; r < 4; ++r) {
      int q = wid * 16 + quad * 4 + r;
      m_arr[rbase + q] = m_i[r];
      l_arr[rbase + q] = l_row[r];
    }
  }
}

// ---------------- Combine attention splits -> ao (bf16) ----------------
__global__ __launch_bounds__(256) void attn_combine(
    const float* __restrict__ O_p, const float* __restrict__ m_arr,
    const float* __restrict__ l_arr, bf16* __restrict__ ao) {
  int t = blockIdx.x * 256 + threadIdx.x;    // over 4096*128
  int d = t & 127, row = t >> 7;             // row=(b*32+h)*64+q
  float m_g = -1e30f;
#pragma unroll
  for (int s = 0; s < NSPL; ++s) m_g = fmaxf(m_g, m_arr[s * 4096 + row]);
  float denom = 0.f, acc = 0.f;
#pragma unroll
  for (int s = 0; s < NSPL; ++s) {
    float w = __expf(m_arr[s * 4096 + row] - m_g);
    denom += w * l_arr[s * 4096 + row];
    acc   += w * O_p[((size_t)s * 4096 + row) * 128 + d];
  }
  int b = row >> 11, h = (row >> 6) & 31, q = row & 63;
  bf16 o = f2b(acc / denom);
  ((ushort*)ao)[((size_t)(b * 64 + q) * 32 + h) * 128 + d] = *(ushort*)&o;
}

extern "C" void kernel_launch(void* const* d_in, const int* in_sizes, int n_in,
                              void* d_out, int out_size, void* d_ws, size_t ws_size,
                              hipStream_t stream) {
  const float* vlm      = (const float*)d_in[0];
  const float* expe     = (const float*)d_in[1];
  const int*   pos      = (const int*)d_in[2];
  // d_in[3] attention_mask: all-True -> unmasked softmax equivalent
  const float* w_ln_vlm = (const float*)d_in[4];
  // d_in[5] Wq_vlm unused (vlm queries don't affect expert outputs)
  const float* Wk_vlm   = (const float*)d_in[6];
  const float* Wv_vlm   = (const float*)d_in[7];
  // d_in[8] Wo_vlm unused
  const float* w_ln_exp = (const float*)d_in[9];
  const float* Wq_exp   = (const float*)d_in[10];
  const float* Wk_exp   = (const float*)d_in[11];
  const float* Wv_exp   = (const float*)d_in[12];
  const float* Wo_exp   = (const float*)d_in[13];
  float* out = (float*)d_out;
  char* ws = (char*)d_ws;

  bf16* hv_b  = (bf16*)(ws + OFF_HVB);
  bf16* WkvT  = (bf16*)(ws + OFF_WKVT);
  bf16* he_b  = (bf16*)(ws + OFF_HEB);
  bf16* WqkvT = (bf16*)(ws + OFF_WQKVT);
  bf16* qe    = (bf16*)(ws + OFF_QE);
  bf16* kbuf  = (bf16*)(ws + OFF_KBUF);
  bf16* vbuf  = (bf16*)(ws + OFF_VBUF);
  bf16* ao    = (bf16*)(ws + OFF_AO);
  float* O_p   = (float*)(ws + OFF_OP);
  float* m_arr = (float*)(ws + OFF_M);
  float* l_arr = (float*)(ws + OFF_L);

  // 0) pre-fill output with residual (D2D, graph-safe)
  hipMemcpyAsync(out, expe, (size_t)B_ * LE_ * DE_ * sizeof(float),
                 hipMemcpyDeviceToDevice, stream);

  // 1) RMSNorm (vlm + expert) -> bf16, one dispatch
  rmsnorm_both<<<B_ * LV_ + B_ * LE_, 256, 0, stream>>>(
      vlm, w_ln_vlm, hv_b, expe, w_ln_exp, he_b);

  // 2) all pre-GEMM weight transpose-converts, one dispatch
  tconv_all<<<4160, 256, 0, stream>>>(Wk_vlm, Wv_vlm, Wq_exp, Wk_exp, Wv_exp,
                                      WkvT, WqkvT);

  // 3) fused GEMM: blocks 0..1023 vlm K/V (M=2048,N=2048,K=2560, 64x64 tiles),
  //    blocks 1024..1215 expert QKV (M=128,N=6144,K=1920), bf16 epilogue
  gemm_fused<<<1216, 256, 0, stream>>>(hv_b, WkvT, he_b, WqkvT, kbuf, vbuf, qe);

  // 4) RoPE (Q + K in-place), one dispatch
  rope_fused<<<128 + B_ * S_TOT, 256, 0, stream>>>(qe, kbuf, pos);

  // 5) flash attention, 9 key-splits -> partials, then combine
  attn_part<<<64 * NSPL, 256, 0, stream>>>(qe, kbuf, vbuf, O_p, m_arr, l_arr);
  attn_combine<<<4096 * 128 / 256, 256, 0, stream>>>(O_p, m_arr, l_arr, ao);

  // 6) output projection, split-K, atomic f32 accumulate into out (+residual)
  gemm_out<<<dim3(30, 16), 256, 0, stream>>>(ao, Wo_exp, out);
}

// Round 7
// 303.008 us; speedup vs baseline: 1.0115x; 1.0048x over previous
//
#include <hip/hip_runtime.h>
#include <hip/hip_bf16.h>
#include <cstddef>

// Problem constants
#define B_  2
#define LV_ 1024
#define LE_ 64
#define S_TOT 1088          // LV+LE
#define DV_ 2560
#define DE_ 1920
#define H_  32
#define KVH_ 8
#define DH_ 128
#define HD_ 4096            // H*DH
#define KVD_ 1024           // KVH*DH
#define NSPL 9              // attention key splits (8x128 + 1x64)

typedef short short8 __attribute__((ext_vector_type(8)));
typedef float f32x4 __attribute__((ext_vector_type(4)));

typedef __hip_bfloat16 bf16;

__device__ inline float b2f(bf16 h) { return __bfloat162float(h); }
__device__ inline bf16 f2b(float f) { return __float2bfloat16(f); }

// global -> LDS direct copy, 16B per lane (dest = wave-uniform base + lane*16)
typedef const __attribute__((address_space(1))) void* gptr_t;
typedef __attribute__((address_space(3))) void* lptr_t;
__device__ inline void gl16(const void* g, void* l) {
  __builtin_amdgcn_global_load_lds((gptr_t)g, (lptr_t)l, 16, 0, 0);
}

// ---------------- Workspace layout (byte offsets) ----------------
// hv_b   : 2048x2560 bf16 @ 0           (10,485,760)
// WkvT   : 2048x2560 bf16 @ 10,485,760  (10,485,760)
// he_b   : 128x1920 bf16  @ 20,971,520  (491,520)
// WqkvT  : 6144x1920 bf16 @ 21,463,040  (23,592,960)
// qe     : 128x4096 bf16  @ 45,056,000  (1,048,576)
// kbuf   : 2x1088x1024 row-major [b][s][kvh][d] @ 46,104,576  (4,456,448)
// vbufT  : TRANSPOSED [b][kvh][d][s]            @ 50,561,024  (4,456,448)
// ao     : 128x4096 bf16  @ 59,473,920  (1,048,576)
// Aliases — all of [0, 45,056,000) is dead after gemm_fused:
//  O_p   : 9x4096x128 f32 (18,874,368) @ 0
//  m_arr : 9x4096 f32 (147,456)        @ 18,874,368
//  l_arr : 9x4096 f32 (147,456)        @ 19,021,824   (end 19,169,280 < qe)
#define OFF_HVB   0ul
#define OFF_WKVT  10485760ul
#define OFF_HEB   20971520ul
#define OFF_WQKVT 21463040ul
#define OFF_QE    45056000ul
#define OFF_KBUF  46104576ul
#define OFF_VBUF  50561024ul
#define OFF_AO    59473920ul
#define OFF_OP    0ul
#define OFF_M     18874368ul
#define OFF_L     19021824ul

// ---------------- Fused RMSNorm (vlm rows 0..2047, expert rest) -> bf16 ----
// Expert branch also pre-fills `out` with the residual (replaces D2D memcpy).
__global__ __launch_bounds__(256) void rmsnorm_both(
    const float* __restrict__ xv, const float* __restrict__ wv,
    bf16* __restrict__ ov,
    const float* __restrict__ xe, const float* __restrict__ we,
    bf16* __restrict__ oe, float* __restrict__ outres) {
  int row; const float* x; const float* w; bf16* o; int D; bool expert;
  if (blockIdx.x < 2048) { row = blockIdx.x;        x = xv; w = wv; o = ov; D = DV_; expert = false; }
  else                   { row = blockIdx.x - 2048; x = xe; w = we; o = oe; D = DE_; expert = true; }
  const float4* x4 = (const float4*)(x + (size_t)row * D);
  const float4* w4 = (const float4*)w;
  float4* res4 = (float4*)(outres + (size_t)row * DE_);
  int D4 = D >> 2;
  float ss = 0.f;
  for (int i = threadIdx.x; i < D4; i += 256) {
    float4 v = x4[i];
    ss += v.x * v.x + v.y * v.y + v.z * v.z + v.w * v.w;
  }
  __shared__ float red[256];
  red[threadIdx.x] = ss; __syncthreads();
  for (int s = 128; s > 0; s >>= 1) {
    if (threadIdx.x < s) red[threadIdx.x] += red[threadIdx.x + s];
    __syncthreads();
  }
  float inv = rsqrtf(red[0] / (float)D + 1e-6f);
  ushort4* o4 = (ushort4*)(o + (size_t)row * D);
  for (int i = threadIdx.x; i < D4; i += 256) {
    float4 v = x4[i], wv2 = w4[i];
    if (expert) res4[i] = v;                    // residual pre-fill
    bf16 a = f2b(v.x * inv * wv2.x), b = f2b(v.y * inv * wv2.y);
    bf16 c = f2b(v.z * inv * wv2.z), d = f2b(v.w * inv * wv2.w);
    ushort4 ow;
    ow.x = *(ushort*)&a; ow.y = *(ushort*)&b; ow.z = *(ushort*)&c; ow.w = *(ushort*)&d;
    o4[i] = ow;
  }
}

// ---------------- 64x64 transpose-convert tile helper ----------------
__device__ inline void tile_tconv(float (*t)[65],
    const float* __restrict__ W, bf16* __restrict__ Wt,
    int K, int N, int n_off, int bx, int by) {
  int n0 = bx * 64, k0 = by * 64;
  int tid = threadIdx.x;
  int c = tid & 63, r4 = tid >> 6;
#pragma unroll 4
  for (int it = 0; it < 16; ++it) {
    int k = it * 4 + r4;
    t[k][c] = W[(size_t)(k0 + k) * N + n0 + c];
  }
  __syncthreads();
#pragma unroll 4
  for (int it = 0; it < 16; ++it) {
    int n = it * 4 + r4;
    Wt[(size_t)(n_off + n0 + n) * K + k0 + c] = f2b(t[c][n]);
  }
}

// fused: all 5 pre-GEMM weight converts in one dispatch (4160 blocks)
__global__ __launch_bounds__(256) void tconv_all(
    const float* __restrict__ Wk_vlm, const float* __restrict__ Wv_vlm,
    const float* __restrict__ Wq_exp, const float* __restrict__ Wk_exp,
    const float* __restrict__ Wv_exp,
    bf16* __restrict__ WkvT, bf16* __restrict__ WqkvT) {
  __shared__ float t[64][65];
  int id = blockIdx.x;
  if (id < 640)       tile_tconv(t, Wk_vlm, WkvT, DV_, KVD_, 0,    id % 16, id / 16);
  else if (id < 1280) { id -= 640;  tile_tconv(t, Wv_vlm, WkvT,  DV_, KVD_, 1024, id % 16, id / 16); }
  else if (id < 3200) { id -= 1280; tile_tconv(t, Wq_exp, WqkvT, DE_, HD_,  0,    id % 64, id / 64); }
  else if (id < 3680) { id -= 3200; tile_tconv(t, Wk_exp, WqkvT, DE_, KVD_, 4096, id % 16, id / 16); }
  else                { id -= 3680; tile_tconv(t, Wv_exp, WqkvT, DE_, KVD_, 5120, id % 16, id / 16); }
}

// ---------------- Fused MFMA GEMM: vlm K/V (blocks 0..1023) + expert QKV ----
// 64x64 tile, 4 waves (2x2 of 32x32). Structurally converged at ~16% MfmaUtil
// (R2-R6: invariant across tile geometry / pipeline depth / occupancy).
// V is written TRANSPOSED [b][kvh][d][s] — the f32x4 acc rows are consecutive
// s, so this packs into 8B ushort4 stores (better than the old scattered
// column writes) and removes attn_part's scalar LDS transpose.
__global__ __launch_bounds__(256) void gemm_fused(
    const bf16* __restrict__ hv, const bf16* __restrict__ WkvT,
    const bf16* __restrict__ he, const bf16* __restrict__ WqkvT,
    bf16* __restrict__ kbuf, bf16* __restrict__ vbufT, bf16* __restrict__ qe) {
  __shared__ ushort As[3][64][32];
  __shared__ ushort Bs[3][64][32];
  int tid = threadIdx.x;
  int lane = tid & 63, w = tid >> 6;
  int lr = lane & 15, quad = lane >> 4;
  int wm = (w >> 1) * 32, wn = (w & 1) * 32;

  bool expert = (blockIdx.x >= 1024);
  const ushort* Ab; const ushort* Bb; int K, nsteps, m0, n0;
  if (!expert) {
    m0 = (int)(blockIdx.x >> 5) * 64; n0 = (int)(blockIdx.x & 31) * 64;
    Ab = (const ushort*)hv; Bb = (const ushort*)WkvT;
    K = DV_; nsteps = DV_ / 32;
  } else {
    int e = (int)blockIdx.x - 1024;
    m0 = (e / 96) * 64; n0 = (e % 96) * 64;
    Ab = (const ushort*)he; Bb = (const ushort*)WqkvT;
    K = DE_; nsteps = DE_ / 32;
  }

  // per-lane pre-swizzled global source pointers (1 A + 1 B gl16 per wave)
  int rr = w * 16 + (lane >> 2);           // row covered by this lane
  int ss = (lane & 3) ^ ((rr >> 1) & 3);   // swizzled 16B slot
  const ushort* pa = Ab + (size_t)(m0 + rr) * K + ss * 8;
  const ushort* pb = Bb + (size_t)(n0 + rr) * K + ss * 8;

  auto STAGE = [&](int buf, int t) {
    int k0 = t * 32;
    gl16(pa + k0, &As[buf][w * 16][0]);
    gl16(pb + k0, &Bs[buf][w * 16][0]);
  };

  int sslot = (quad ^ ((lr >> 1) & 3)) * 8;   // fragment-read swizzled slot

  f32x4 acc[2][2] = {};

  STAGE(0, 0);
  STAGE(1, 1);
  int cur = 0, nxt = 2;
  for (int t = 0; t < nsteps; ++t) {
    int rem = nsteps - t;
    if (rem > 2) {
      STAGE(nxt, t + 2);
      asm volatile("s_waitcnt vmcnt(4)" ::: "memory");
    } else if (rem == 2) {
      asm volatile("s_waitcnt vmcnt(2)" ::: "memory");
    } else {
      asm volatile("s_waitcnt vmcnt(0)" ::: "memory");
    }
    __builtin_amdgcn_s_barrier();

    short8 af[2], bv[2];
#pragma unroll
    for (int i = 0; i < 2; ++i) {
      af[i] = *(const short8*)&As[cur][wm + i * 16 + lr][sslot];
      bv[i] = *(const short8*)&Bs[cur][wn + i * 16 + lr][sslot];
    }
    __builtin_amdgcn_s_setprio(1);
#pragma unroll
    for (int i = 0; i < 2; ++i)
#pragma unroll
      for (int j = 0; j < 2; ++j)
        acc[i][j] = __builtin_amdgcn_mfma_f32_16x16x32_bf16(af[i], bv[j], acc[i][j], 0, 0, 0);
    __builtin_amdgcn_s_setprio(0);

    __builtin_amdgcn_s_barrier();
    cur = (cur == 2) ? 0 : cur + 1;
    nxt = (nxt == 2) ? 0 : nxt + 1;
  }

  // ---- epilogue ----
#pragma unroll
  for (int i = 0; i < 2; ++i) {
    int mm_base = wm + i * 16 + quad * 4;      // 4 consecutive m rows
#pragma unroll
    for (int j = 0; j < 2; ++j) {
      int gn = n0 + wn + j * 16 + lr;
      int m = m0 + mm_base;
      if (!expert) {
        int b = m >> 10, s = m & 1023;
        if (gn < 1024) {
          size_t row = (size_t)(b * S_TOT + s);
#pragma unroll
          for (int r = 0; r < 4; ++r)
            kbuf[(row + r) * KVD_ + gn] = f2b(acc[i][j][r]);
        } else {
          int d = gn - 1024, kvh = d >> 7, dd = d & 127;
          ushort4 o;
          bf16 h0 = f2b(acc[i][j][0]), h1 = f2b(acc[i][j][1]);
          bf16 h2 = f2b(acc[i][j][2]), h3 = f2b(acc[i][j][3]);
          o.x = *(ushort*)&h0; o.y = *(ushort*)&h1; o.z = *(ushort*)&h2; o.w = *(ushort*)&h3;
          *(ushort4*)((ushort*)vbufT +
              ((size_t)(b * KVH_ + kvh) * DH_ + dd) * S_TOT + s) = o;
        }
      } else {
        int b = m >> 6, l = m & 63;
        if (gn < 4096) {
#pragma unroll
          for (int r = 0; r < 4; ++r)
            qe[(size_t)(m + r) * HD_ + gn] = f2b(acc[i][j][r]);
        } else if (gn < 5120) {
          size_t row = (size_t)(b * S_TOT + LV_ + l);
#pragma unroll
          for (int r = 0; r < 4; ++r)
            kbuf[(row + r) * KVD_ + (gn - 4096)] = f2b(acc[i][j][r]);
        } else {
          int d = gn - 5120, kvh = d >> 7, dd = d & 127;
          ushort4 o;
          bf16 h0 = f2b(acc[i][j][0]), h1 = f2b(acc[i][j][1]);
          bf16 h2 = f2b(acc[i][j][2]), h3 = f2b(acc[i][j][3]);
          o.x = *(ushort*)&h0; o.y = *(ushort*)&h1; o.z = *(ushort*)&h2; o.w = *(ushort*)&h3;
          *(ushort4*)((ushort*)vbufT +
              ((size_t)(b * KVH_ + kvh) * DH_ + dd) * S_TOT + (LV_ + l)) = o;
        }
      }
    }
  }
}

// ---------------- Output projection split-K GEMM, B = Wo f32 row-major ----
// C = ao(128xHD) * Wo(HD x 1920), K-split 16 x 256, N-tile 64.
// Accumulates into out (pre-filled with residual) via f32 atomics.
__global__ __launch_bounds__(256) void gemm_out(
    const bf16* __restrict__ A, const float* __restrict__ W,
    float* __restrict__ out) {
  __shared__ ushort As[128][40];
  __shared__ ushort Bs[64][40];
  int tid = threadIdx.x;
  int lane = tid & 63, wid = tid >> 6;
  int wm = (wid >> 1) * 64, wn = (wid & 1) * 32;
  int n0 = blockIdx.x * 64;
  int k_beg = blockIdx.y * 256;
  int lr = lane & 15, quad = lane >> 4;

  f32x4 acc[4][2] = {};

  int ar = tid >> 2;
  int ac = (tid & 3) * 8;
  const ushort* Aptr = (const ushort*)A + (size_t)ar * HD_ + ac;
  int bn = tid & 63, kg = tid >> 6;              // B-stage: col n0+bn, rows kg*8..+7
  int bslot_w = ((kg ^ (bn & 3)) * 8);
  int brd = (quad ^ (lr & 3)) * 8;               // fragment-read slot

  for (int k0 = k_beg; k0 < k_beg + 256; k0 += 32) {
    short8 a0 = *(const short8*)(Aptr + k0);
    short8 a1 = *(const short8*)(Aptr + (size_t)64 * HD_ + k0);
    float wv[8];
#pragma unroll
    for (int j = 0; j < 8; ++j)
      wv[j] = W[(size_t)(k0 + kg * 8 + j) * DE_ + n0 + bn];
    short8 bvv;
#pragma unroll
    for (int j = 0; j < 8; ++j) { bf16 h = f2b(wv[j]); bvv[j] = *(short*)&h; }
    __syncthreads();
    *(short8*)&As[ar][ac] = a0;
    *(short8*)&As[64 + ar][ac] = a1;
    *(short8*)&Bs[bn][bslot_w] = bvv;
    __syncthreads();
    short8 af[4], bfr[2];
#pragma unroll
    for (int i = 0; i < 4; ++i)
      af[i]  = *(const short8*)&As[wm + i * 16 + lr][quad * 8];
#pragma unroll
    for (int j = 0; j < 2; ++j)
      bfr[j] = *(const short8*)&Bs[wn + j * 16 + lr][brd];
#pragma unroll
    for (int i = 0; i < 4; ++i)
#pragma unroll
      for (int j = 0; j < 2; ++j)
        acc[i][j] = __builtin_amdgcn_mfma_f32_16x16x32_bf16(af[i], bfr[j], acc[i][j], 0, 0, 0);
  }

#pragma unroll
  for (int i = 0; i < 4; ++i) {
    int m_base = wm + i * 16 + quad * 4;
#pragma unroll
    for (int j = 0; j < 2; ++j) {
      int gn = n0 + wn + j * 16 + lr;
#pragma unroll
      for (int r = 0; r < 4; ++r)
        atomicAdd(&out[(size_t)(m_base + r) * 1920 + gn], acc[i][j][r]);
    }
  }
}

// ---------------- Fused RoPE: Q (blocks 0..127) and K in-place (rest) ----------------
__global__ __launch_bounds__(256) void rope_fused(
    bf16* __restrict__ qe, bf16* __restrict__ kbuf,
    const int* __restrict__ pos_ids) {
  if (blockIdx.x < 128) {
    int row = blockIdx.x;
    int b = row >> 6, l = row & 63;
    float pos = (float)pos_ids[b * S_TOT + LV_ + l];
    bf16* qrow = qe + (size_t)row * HD_;
    for (int p = threadIdx.x; p < H_ * 64; p += 256) {
      int hh = p >> 6, i = p & 63;
      float inv_ts = expf(-9.210340371976184f * (float)i * (1.0f / 64.0f));
      float r = pos * inv_ts;
      float sn = sinf(r), cs = cosf(r);
      float x1 = b2f(qrow[hh * DH_ + i]), x2 = b2f(qrow[hh * DH_ + i + 64]);
      qrow[hh * DH_ + i]      = f2b(x1 * cs - x2 * sn);
      qrow[hh * DH_ + i + 64] = f2b(x2 * cs + x1 * sn);
    }
  } else {
    int bid = blockIdx.x - 128;
    int s = bid % S_TOT, b = bid / S_TOT;
    float pos = (float)pos_ids[b * S_TOT + s];
    size_t base = ((size_t)(b * S_TOT + s)) * KVD_;
    for (int t = threadIdx.x; t < KVH_ * 64; t += 256) {
      int kvh = t >> 6, i = t & 63;
      size_t idx = base + kvh * DH_ + i;
      float inv_ts = expf(-9.210340371976184f * (float)i * (1.0f / 64.0f));
      float r = pos * inv_ts;
      float sn = sinf(r), cs = cosf(r);
      float x1 = b2f(kbuf[idx]), x2 = b2f(kbuf[idx + 64]);
      kbuf[idx]      = f2b(x1 * cs - x2 * sn);
      kbuf[idx + 64] = f2b(x2 * cs + x1 * sn);
    }
  }
}

// ---------------- MFMA flash attention, split over keys ----------------
// grid: 576 = (b,h) x 9 splits. Splits 0..7: 128 keys (2 chunks); split 8: 64.
// R7: V arrives pre-transposed [b][kvh][d][s] -> vector staging (short8),
// no scalar transpose; vTs/sc strides moved 72->80 ushorts (160B = 8 dw mod
// 32) to break the 8-way PV fragment-read bank conflict while keeping 16B
// alignment for ds_read_b128.
__global__ __launch_bounds__(256) void attn_part(
    const bf16* __restrict__ qe, const bf16* __restrict__ kbuf,
    const bf16* __restrict__ vbufT,
    float* __restrict__ O_p, float* __restrict__ m_arr,
    float* __restrict__ l_arr) {
  int bh = blockIdx.x & 63;              // (b<<5)|h
  int split = blockIdx.x >> 6;           // 0..8
  int h = bh & 31, b = bh >> 5;
  int kvh = h >> 2;                      // G=4
  int tid = threadIdx.x;
  int lane = tid & 63, wid = tid >> 6;
  int lr = lane & 15, quad = lane >> 4;

  __shared__ ushort Ks[64][152];
  __shared__ ushort vTs[128][80];
  __shared__ ushort sc[4][16][80];

  // Q A-fragments: lane holds Q[m=lr][k=quad*8+j], 4 k-steps of 32
  short8 qf[4];
  {
    const ushort* qptr = (const ushort*)qe +
        ((size_t)(b * LE_ + wid * 16 + lr)) * HD_ + h * DH_ + quad * 8;
#pragma unroll
    for (int ks = 0; ks < 4; ++ks) qf[ks] = *(const short8*)(qptr + ks * 32);
  }

  f32x4 Of[8] = {};                      // O C-frags: row=quad*4+r, col=lr+16*nt
  float m_i[4], l_i[4];
#pragma unroll
  for (int r = 0; r < 4; ++r) { m_i[r] = -1e30f; l_i[r] = 0.f; }

  const float scale = 0.08838834764831845f;   // 128^-0.5
  int nch = (split == 8) ? 1 : 2;
  const ushort* vtb = (const ushort*)vbufT +
      (size_t)(b * KVH_ + kvh) * DH_ * S_TOT;

  for (int c = 0; c < nch; ++c) {
    int key0 = split * 128 + c * 64;
    __syncthreads();
    // ---- stage K chunk (64 keys x 128 d), row-major ----
    {
      int dg = tid & 15, kq = tid >> 4;       // 16 keys per iter
#pragma unroll
      for (int it = 0; it < 4; ++it) {
        int key = it * 16 + kq;
        short8 v = *(const short8*)((const ushort*)kbuf +
            ((size_t)(b * S_TOT + key0 + key) * KVH_ + kvh) * DH_ + dg * 8);
        *(short8*)&Ks[key][dg * 8] = v;
      }
    }
    // ---- stage V chunk from transposed layout: vTs[d][key] (vector copy) ----
    {
      int dd = tid >> 3, kk = (tid & 7) * 8;
#pragma unroll
      for (int it = 0; it < 4; ++it) {
        int d = it * 32 + dd;
        short8 v = *(const short8*)(vtb + (size_t)d * S_TOT + key0 + kk);
        *(short8*)&vTs[d][kk] = v;
      }
    }
    __syncthreads();

    // ---- QK^T: S (16q x 64k) in 4 C-frags ----
    f32x4 Sf[4] = {};
#pragma unroll
    for (int kt = 0; kt < 4; ++kt)
#pragma unroll
      for (int ks = 0; ks < 4; ++ks) {
        short8 kf = *(const short8*)&Ks[kt * 16 + lr][quad * 8 + ks * 32];
        Sf[kt] = __builtin_amdgcn_mfma_f32_16x16x32_bf16(qf[ks], kf, Sf[kt], 0, 0, 0);
      }

    // ---- online softmax (rows r -> q = quad*4+r) ----
#pragma unroll
    for (int kt = 0; kt < 4; ++kt) Sf[kt] *= scale;
#pragma unroll
    for (int r = 0; r < 4; ++r) {
      float mx = fmaxf(fmaxf(Sf[0][r], Sf[1][r]), fmaxf(Sf[2][r], Sf[3][r]));
#pragma unroll
      for (int msk = 1; msk < 16; msk <<= 1) mx = fmaxf(mx, __shfl_xor(mx, msk));
      float mn = fmaxf(m_i[r], mx);
      float alpha = __expf(m_i[r] - mn);
      m_i[r] = mn;
      float ls = 0.f;
#pragma unroll
      for (int kt = 0; kt < 4; ++kt) {
        float p = __expf(Sf[kt][r] - mn);
        Sf[kt][r] = p;
        ls += p;
      }
      l_i[r] = l_i[r] * alpha + ls;
#pragma unroll
      for (int nt = 0; nt < 8; ++nt) Of[nt][r] *= alpha;
#pragma unroll
      for (int kt = 0; kt < 4; ++kt) {
        bf16 t = f2b(Sf[kt][r]);
        sc[wid][quad * 4 + r][kt * 16 + lr] = *(ushort*)&t;
      }
    }

    // ---- PV: O += P (16x64) * V (64x128) ----
#pragma unroll
    for (int ks = 0; ks < 2; ++ks) {
      short8 pf = *(const short8*)&sc[wid][lr][quad * 8 + ks * 32];
#pragma unroll
      for (int nt = 0; nt < 8; ++nt) {
        short8 vf = *(const short8*)&vTs[nt * 16 + lr][quad * 8 + ks * 32];
        Of[nt] = __builtin_amdgcn_mfma_f32_16x16x32_bf16(pf, vf, Of[nt], 0, 0, 0);
      }
    }
  }

  // ---- finalize l: sum across the 16-lane lr group for the true row sum ----
  float l_row[4];
#pragma unroll
  for (int r = 0; r < 4; ++r) {
    float l = l_i[r];
#pragma unroll
    for (int msk = 1; msk < 16; msk <<= 1) l += __shfl_xor(l, msk);
    l_row[r] = l;
  }

  // ---- write partials: O_p[(split*4096 + row)*128 + d], row=(b*32+h)*64+q ----
  size_t rbase = (size_t)split * 4096 + (size_t)bh * 64;
#pragma unroll
  for (int nt = 0; nt < 8; ++nt)
#pragma unroll
    for (int r = 0; r < 4; ++r) {
      int q = wid * 16 + quad * 4 + r;
      O_p[(rbase + q) * 128 + nt * 16 + lr] = Of[nt][r];
    }
  if (lr == 0) {
#pragma unroll
    for (int r = 0; r < 4; ++r) {
      int q = wid * 16 + quad * 4 + r;
      m_arr[rbase + q] = m_i[r];
      l_arr[rbase + q] = l_row[r];
    }
  }
}

// ---------------- Combine attention splits -> ao (bf16) ----------------
__global__ __launch_bounds__(256) void attn_combine(
    const float* __restrict__ O_p, const float* __restrict__ m_arr,
    const float* __restrict__ l_arr, bf16* __restrict__ ao) {
  int t = blockIdx.x * 256 + threadIdx.x;    // over 4096*128
  int d = t & 127, row = t >> 7;             // row=(b*32+h)*64+q
  float m_g = -1e30f;
#pragma unroll
  for (int s = 0; s < NSPL; ++s) m_g = fmaxf(m_g, m_arr[s * 4096 + row]);
  float denom = 0.f, acc = 0.f;
#pragma unroll
  for (int s = 0; s < NSPL; ++s) {
    float w = __expf(m_arr[s * 4096 + row] - m_g);
    denom += w * l_arr[s * 4096 + row];
    acc   += w * O_p[((size_t)s * 4096 + row) * 128 + d];
  }
  int b = row >> 11, h = (row >> 6) & 31, q = row & 63;
  bf16 o = f2b(acc / denom);
  ((ushort*)ao)[((size_t)(b * 64 + q) * 32 + h) * 128 + d] = *(ushort*)&o;
}

extern "C" void kernel_launch(void* const* d_in, const int* in_sizes, int n_in,
                              void* d_out, int out_size, void* d_ws, size_t ws_size,
                              hipStream_t stream) {
  const float* vlm      = (const float*)d_in[0];
  const float* expe     = (const float*)d_in[1];
  const int*   pos      = (const int*)d_in[2];
  // d_in[3] attention_mask: all-True -> unmasked softmax equivalent
  const float* w_ln_vlm = (const float*)d_in[4];
  // d_in[5] Wq_vlm unused (vlm queries don't affect expert outputs)
  const float* Wk_vlm   = (const float*)d_in[6];
  const float* Wv_vlm   = (const float*)d_in[7];
  // d_in[8] Wo_vlm unused
  const float* w_ln_exp = (const float*)d_in[9];
  const float* Wq_exp   = (const float*)d_in[10];
  const float* Wk_exp   = (const float*)d_in[11];
  const float* Wv_exp   = (const float*)d_in[12];
  const float* Wo_exp   = (const float*)d_in[13];
  float* out = (float*)d_out;
  char* ws = (char*)d_ws;

  bf16* hv_b  = (bf16*)(ws + OFF_HVB);
  bf16* WkvT  = (bf16*)(ws + OFF_WKVT);
  bf16* he_b  = (bf16*)(ws + OFF_HEB);
  bf16* WqkvT = (bf16*)(ws + OFF_WQKVT);
  bf16* qe    = (bf16*)(ws + OFF_QE);
  bf16* kbuf  = (bf16*)(ws + OFF_KBUF);
  bf16* vbufT = (bf16*)(ws + OFF_VBUF);
  bf16* ao    = (bf16*)(ws + OFF_AO);
  float* O_p   = (float*)(ws + OFF_OP);
  float* m_arr = (float*)(ws + OFF_M);
  float* l_arr = (float*)(ws + OFF_L);

  // 1) RMSNorm (vlm + expert) -> bf16; expert branch pre-fills out w/ residual
  rmsnorm_both<<<B_ * LV_ + B_ * LE_, 256, 0, stream>>>(
      vlm, w_ln_vlm, hv_b, expe, w_ln_exp, he_b, out);

  // 2) all pre-GEMM weight transpose-converts, one dispatch
  tconv_all<<<4160, 256, 0, stream>>>(Wk_vlm, Wv_vlm, Wq_exp, Wk_exp, Wv_exp,
                                      WkvT, WqkvT);

  // 3) fused GEMM: blocks 0..1023 vlm K/V (64x64 tiles), blocks 1024..1215
  //    expert QKV; K row-major, V transposed, bf16 epilogue
  gemm_fused<<<1216, 256, 0, stream>>>(hv_b, WkvT, he_b, WqkvT, kbuf, vbufT, qe);

  // 4) RoPE (Q + K in-place), one dispatch
  rope_fused<<<128 + B_ * S_TOT, 256, 0, stream>>>(qe, kbuf, pos);

  // 5) flash attention, 9 key-splits -> partials, then combine
  attn_part<<<64 * NSPL, 256, 0, stream>>>(qe, kbuf, vbufT, O_p, m_arr, l_arr);
  attn_combine<<<4096 * 128 / 256, 256, 0, stream>>>(O_p, m_arr, l_arr, ao);

  // 6) output projection, split-K, atomic f32 accumulate into out (+residual)
  gemm_out<<<dim3(30, 16), 256, 0, stream>>>(ao, Wo_exp, out);
}

// Round 8
// 302.247 us; speedup vs baseline: 1.0141x; 1.0025x over previous
//
#include <hip/hip_runtime.h>
#include <hip/hip_bf16.h>
#include <cstddef>

// Problem constants
#define B_  2
#define LV_ 1024
#define LE_ 64
#define S_TOT 1088          // LV+LE
#define DV_ 2560
#define DE_ 1920
#define H_  32
#define KVH_ 8
#define DH_ 128
#define HD_ 4096            // H*DH
#define KVD_ 1024           // KVH*DH
#define NSPL 9              // attention key splits (8x128 + 1x64)

typedef short short8 __attribute__((ext_vector_type(8)));
typedef float f32x4 __attribute__((ext_vector_type(4)));

typedef __hip_bfloat16 bf16;

__device__ inline float b2f(bf16 h) { return __bfloat162float(h); }
__device__ inline bf16 f2b(float f) { return __float2bfloat16(f); }

// global -> LDS direct copy, 16B per lane (dest = wave-uniform base + lane*16)
typedef const __attribute__((address_space(1))) void* gptr_t;
typedef __attribute__((address_space(3))) void* lptr_t;
__device__ inline void gl16(const void* g, void* l) {
  __builtin_amdgcn_global_load_lds((gptr_t)g, (lptr_t)l, 16, 0, 0);
}

// ---------------- Workspace layout (byte offsets) ----------------
// hv_b   : 2048x2560 bf16 @ 0           (10,485,760)
// WkvT   : 2048x2560 bf16 @ 10,485,760  (10,485,760)
// he_b   : 128x1920 bf16  @ 20,971,520  (491,520)
// WqkvT  : 6144x1920 bf16 @ 21,463,040  (23,592,960)
// qe     : 128x4096 bf16  @ 45,056,000  (1,048,576)
// kbuf   : 2x1088x1024 row-major [b][s][kvh][d] @ 46,104,576  (4,456,448)
// vbufT  : TRANSPOSED [b][kvh][d][s]            @ 50,561,024  (4,456,448)
// ao     : 128x4096 bf16  @ 59,473,920  (1,048,576)
// Aliases — all of [0, 45,056,000) is dead after gemm_fused:
//  O_p   : 9x4096x128 f32 (18,874,368) @ 0
//  m_arr : 9x4096 f32 (147,456)        @ 18,874,368
//  l_arr : 9x4096 f32 (147,456)        @ 19,021,824   (end 19,169,280 < qe)
#define OFF_HVB   0ul
#define OFF_WKVT  10485760ul
#define OFF_HEB   20971520ul
#define OFF_WQKVT 21463040ul
#define OFF_QE    45056000ul
#define OFF_KBUF  46104576ul
#define OFF_VBUF  50561024ul
#define OFF_AO    59473920ul
#define OFF_OP    0ul
#define OFF_M     18874368ul
#define OFF_L     19021824ul

// ---------------- Fused RMSNorm (vlm rows 0..2047, expert rest) -> bf16 ----
// Expert branch also pre-fills `out` with the residual (replaces D2D memcpy).
__global__ __launch_bounds__(256) void rmsnorm_both(
    const float* __restrict__ xv, const float* __restrict__ wv,
    bf16* __restrict__ ov,
    const float* __restrict__ xe, const float* __restrict__ we,
    bf16* __restrict__ oe, float* __restrict__ outres) {
  int row; const float* x; const float* w; bf16* o; int D; bool expert;
  if (blockIdx.x < 2048) { row = blockIdx.x;        x = xv; w = wv; o = ov; D = DV_; expert = false; }
  else                   { row = blockIdx.x - 2048; x = xe; w = we; o = oe; D = DE_; expert = true; }
  const float4* x4 = (const float4*)(x + (size_t)row * D);
  const float4* w4 = (const float4*)w;
  float4* res4 = (float4*)(outres + (size_t)row * DE_);
  int D4 = D >> 2;
  float ss = 0.f;
  for (int i = threadIdx.x; i < D4; i += 256) {
    float4 v = x4[i];
    ss += v.x * v.x + v.y * v.y + v.z * v.z + v.w * v.w;
  }
  __shared__ float red[256];
  red[threadIdx.x] = ss; __syncthreads();
  for (int s = 128; s > 0; s >>= 1) {
    if (threadIdx.x < s) red[threadIdx.x] += red[threadIdx.x + s];
    __syncthreads();
  }
  float inv = rsqrtf(red[0] / (float)D + 1e-6f);
  ushort4* o4 = (ushort4*)(o + (size_t)row * D);
  for (int i = threadIdx.x; i < D4; i += 256) {
    float4 v = x4[i], wv2 = w4[i];
    if (expert) res4[i] = v;                    // residual pre-fill
    bf16 a = f2b(v.x * inv * wv2.x), b = f2b(v.y * inv * wv2.y);
    bf16 c = f2b(v.z * inv * wv2.z), d = f2b(v.w * inv * wv2.w);
    ushort4 ow;
    ow.x = *(ushort*)&a; ow.y = *(ushort*)&b; ow.z = *(ushort*)&c; ow.w = *(ushort*)&d;
    o4[i] = ow;
  }
}

// ---------------- 64x64 transpose-convert tile helper (vectorized R8) ----
// float4 global reads (16B/lane), ushort4 global writes (8B/lane).
// LDS [64][65] scalar access: stride 65 == 1 (mod 32) -> bank =
// (row + 4*c4 + j) mod 32 across lanes = exactly 2 lanes/bank (free, m136).
__device__ inline void tile_tconv(float (*t)[65],
    const float* __restrict__ W, bf16* __restrict__ Wt,
    int K, int N, int n_off, int bx, int by) {
  int n0 = bx * 64, k0 = by * 64;
  int tid = threadIdx.x;
  int g = tid >> 4, c4 = tid & 15;
#pragma unroll
  for (int it = 0; it < 4; ++it) {
    int k = it * 16 + g;
    float4 v = *(const float4*)&W[(size_t)(k0 + k) * N + n0 + c4 * 4];
    t[k][c4 * 4 + 0] = v.x; t[k][c4 * 4 + 1] = v.y;
    t[k][c4 * 4 + 2] = v.z; t[k][c4 * 4 + 3] = v.w;
  }
  __syncthreads();
#pragma unroll
  for (int it = 0; it < 4; ++it) {
    int n = it * 16 + g;
    bf16 h0 = f2b(t[c4 * 4 + 0][n]);
    bf16 h1 = f2b(t[c4 * 4 + 1][n]);
    bf16 h2 = f2b(t[c4 * 4 + 2][n]);
    bf16 h3 = f2b(t[c4 * 4 + 3][n]);
    ushort4 o;
    o.x = *(ushort*)&h0; o.y = *(ushort*)&h1;
    o.z = *(ushort*)&h2; o.w = *(ushort*)&h3;
    *(ushort4*)((ushort*)Wt + (size_t)(n_off + n0 + n) * K + k0 + c4 * 4) = o;
  }
}

// fused: all 5 pre-GEMM weight converts in one dispatch (4160 blocks)
__global__ __launch_bounds__(256) void tconv_all(
    const float* __restrict__ Wk_vlm, const float* __restrict__ Wv_vlm,
    const float* __restrict__ Wq_exp, const float* __restrict__ Wk_exp,
    const float* __restrict__ Wv_exp,
    bf16* __restrict__ WkvT, bf16* __restrict__ WqkvT) {
  __shared__ float t[64][65];
  int id = blockIdx.x;
  if (id < 640)       tile_tconv(t, Wk_vlm, WkvT, DV_, KVD_, 0,    id % 16, id / 16);
  else if (id < 1280) { id -= 640;  tile_tconv(t, Wv_vlm, WkvT,  DV_, KVD_, 1024, id % 16, id / 16); }
  else if (id < 3200) { id -= 1280; tile_tconv(t, Wq_exp, WqkvT, DE_, HD_,  0,    id % 64, id / 64); }
  else if (id < 3680) { id -= 3200; tile_tconv(t, Wk_exp, WqkvT, DE_, KVD_, 4096, id % 16, id / 16); }
  else                { id -= 3680; tile_tconv(t, Wv_exp, WqkvT, DE_, KVD_, 5120, id % 16, id / 16); }
}

// ---------------- Fused MFMA GEMM: vlm K/V (blocks 0..1023) + expert QKV ----
// 64x64 tile, 4 waves (2x2 of 32x32). Structurally converged at ~16% MfmaUtil
// (R2-R7: invariant across tile geometry / pipeline depth / occupancy).
// V is written TRANSPOSED [b][kvh][d][s].
__global__ __launch_bounds__(256) void gemm_fused(
    const bf16* __restrict__ hv, const bf16* __restrict__ WkvT,
    const bf16* __restrict__ he, const bf16* __restrict__ WqkvT,
    bf16* __restrict__ kbuf, bf16* __restrict__ vbufT, bf16* __restrict__ qe) {
  __shared__ ushort As[3][64][32];
  __shared__ ushort Bs[3][64][32];
  int tid = threadIdx.x;
  int lane = tid & 63, w = tid >> 6;
  int lr = lane & 15, quad = lane >> 4;
  int wm = (w >> 1) * 32, wn = (w & 1) * 32;

  bool expert = (blockIdx.x >= 1024);
  const ushort* Ab; const ushort* Bb; int K, nsteps, m0, n0;
  if (!expert) {
    m0 = (int)(blockIdx.x >> 5) * 64; n0 = (int)(blockIdx.x & 31) * 64;
    Ab = (const ushort*)hv; Bb = (const ushort*)WkvT;
    K = DV_; nsteps = DV_ / 32;
  } else {
    int e = (int)blockIdx.x - 1024;
    m0 = (e / 96) * 64; n0 = (e % 96) * 64;
    Ab = (const ushort*)he; Bb = (const ushort*)WqkvT;
    K = DE_; nsteps = DE_ / 32;
  }

  // per-lane pre-swizzled global source pointers (1 A + 1 B gl16 per wave)
  int rr = w * 16 + (lane >> 2);           // row covered by this lane
  int ss = (lane & 3) ^ ((rr >> 1) & 3);   // swizzled 16B slot
  const ushort* pa = Ab + (size_t)(m0 + rr) * K + ss * 8;
  const ushort* pb = Bb + (size_t)(n0 + rr) * K + ss * 8;

  auto STAGE = [&](int buf, int t) {
    int k0 = t * 32;
    gl16(pa + k0, &As[buf][w * 16][0]);
    gl16(pb + k0, &Bs[buf][w * 16][0]);
  };

  int sslot = (quad ^ ((lr >> 1) & 3)) * 8;   // fragment-read swizzled slot

  f32x4 acc[2][2] = {};

  STAGE(0, 0);
  STAGE(1, 1);
  int cur = 0, nxt = 2;
  for (int t = 0; t < nsteps; ++t) {
    int rem = nsteps - t;
    if (rem > 2) {
      STAGE(nxt, t + 2);
      asm volatile("s_waitcnt vmcnt(4)" ::: "memory");
    } else if (rem == 2) {
      asm volatile("s_waitcnt vmcnt(2)" ::: "memory");
    } else {
      asm volatile("s_waitcnt vmcnt(0)" ::: "memory");
    }
    __builtin_amdgcn_s_barrier();

    short8 af[2], bv[2];
#pragma unroll
    for (int i = 0; i < 2; ++i) {
      af[i] = *(const short8*)&As[cur][wm + i * 16 + lr][sslot];
      bv[i] = *(const short8*)&Bs[cur][wn + i * 16 + lr][sslot];
    }
    __builtin_amdgcn_s_setprio(1);
#pragma unroll
    for (int i = 0; i < 2; ++i)
#pragma unroll
      for (int j = 0; j < 2; ++j)
        acc[i][j] = __builtin_amdgcn_mfma_f32_16x16x32_bf16(af[i], bv[j], acc[i][j], 0, 0, 0);
    __builtin_amdgcn_s_setprio(0);

    __builtin_amdgcn_s_barrier();
    cur = (cur == 2) ? 0 : cur + 1;
    nxt = (nxt == 2) ? 0 : nxt + 1;
  }

  // ---- epilogue ----
#pragma unroll
  for (int i = 0; i < 2; ++i) {
    int mm_base = wm + i * 16 + quad * 4;      // 4 consecutive m rows
#pragma unroll
    for (int j = 0; j < 2; ++j) {
      int gn = n0 + wn + j * 16 + lr;
      int m = m0 + mm_base;
      if (!expert) {
        int b = m >> 10, s = m & 1023;
        if (gn < 1024) {
          size_t row = (size_t)(b * S_TOT + s);
#pragma unroll
          for (int r = 0; r < 4; ++r)
            kbuf[(row + r) * KVD_ + gn] = f2b(acc[i][j][r]);
        } else {
          int d = gn - 1024, kvh = d >> 7, dd = d & 127;
          ushort4 o;
          bf16 h0 = f2b(acc[i][j][0]), h1 = f2b(acc[i][j][1]);
          bf16 h2 = f2b(acc[i][j][2]), h3 = f2b(acc[i][j][3]);
          o.x = *(ushort*)&h0; o.y = *(ushort*)&h1; o.z = *(ushort*)&h2; o.w = *(ushort*)&h3;
          *(ushort4*)((ushort*)vbufT +
              ((size_t)(b * KVH_ + kvh) * DH_ + dd) * S_TOT + s) = o;
        }
      } else {
        int b = m >> 6, l = m & 63;
        if (gn < 4096) {
#pragma unroll
          for (int r = 0; r < 4; ++r)
            qe[(size_t)(m + r) * HD_ + gn] = f2b(acc[i][j][r]);
        } else if (gn < 5120) {
          size_t row = (size_t)(b * S_TOT + LV_ + l);
#pragma unroll
          for (int r = 0; r < 4; ++r)
            kbuf[(row + r) * KVD_ + (gn - 4096)] = f2b(acc[i][j][r]);
        } else {
          int d = gn - 5120, kvh = d >> 7, dd = d & 127;
          ushort4 o;
          bf16 h0 = f2b(acc[i][j][0]), h1 = f2b(acc[i][j][1]);
          bf16 h2 = f2b(acc[i][j][2]), h3 = f2b(acc[i][j][3]);
          o.x = *(ushort*)&h0; o.y = *(ushort*)&h1; o.z = *(ushort*)&h2; o.w = *(ushort*)&h3;
          *(ushort4*)((ushort*)vbufT +
              ((size_t)(b * KVH_ + kvh) * DH_ + dd) * S_TOT + (LV_ + l)) = o;
        }
      }
    }
  }
}

// ---------------- Output projection split-K GEMM, B = Wo f32 row-major ----
// C = ao(128xHD) * Wo(HD x 1920), K-split 16 x 256, N-tile 64.
// Accumulates into out (pre-filled with residual) via f32 atomics.
__global__ __launch_bounds__(256) void gemm_out(
    const bf16* __restrict__ A, const float* __restrict__ W,
    float* __restrict__ out) {
  __shared__ ushort As[128][40];
  __shared__ ushort Bs[64][40];
  int tid = threadIdx.x;
  int lane = tid & 63, wid = tid >> 6;
  int wm = (wid >> 1) * 64, wn = (wid & 1) * 32;
  int n0 = blockIdx.x * 64;
  int k_beg = blockIdx.y * 256;
  int lr = lane & 15, quad = lane >> 4;

  f32x4 acc[4][2] = {};

  int ar = tid >> 2;
  int ac = (tid & 3) * 8;
  const ushort* Aptr = (const ushort*)A + (size_t)ar * HD_ + ac;
  int bn = tid & 63, kg = tid >> 6;              // B-stage: col n0+bn, rows kg*8..+7
  int bslot_w = ((kg ^ (bn & 3)) * 8);
  int brd = (quad ^ (lr & 3)) * 8;               // fragment-read slot

  for (int k0 = k_beg; k0 < k_beg + 256; k0 += 32) {
    short8 a0 = *(const short8*)(Aptr + k0);
    short8 a1 = *(const short8*)(Aptr + (size_t)64 * HD_ + k0);
    float wv[8];
#pragma unroll
    for (int j = 0; j < 8; ++j)
      wv[j] = W[(size_t)(k0 + kg * 8 + j) * DE_ + n0 + bn];
    short8 bvv;
#pragma unroll
    for (int j = 0; j < 8; ++j) { bf16 h = f2b(wv[j]); bvv[j] = *(short*)&h; }
    __syncthreads();
    *(short8*)&As[ar][ac] = a0;
    *(short8*)&As[64 + ar][ac] = a1;
    *(short8*)&Bs[bn][bslot_w] = bvv;
    __syncthreads();
    short8 af[4], bfr[2];
#pragma unroll
    for (int i = 0; i < 4; ++i)
      af[i]  = *(const short8*)&As[wm + i * 16 + lr][quad * 8];
#pragma unroll
    for (int j = 0; j < 2; ++j)
      bfr[j] = *(const short8*)&Bs[wn + j * 16 + lr][brd];
#pragma unroll
    for (int i = 0; i < 4; ++i)
#pragma unroll
      for (int j = 0; j < 2; ++j)
        acc[i][j] = __builtin_amdgcn_mfma_f32_16x16x32_bf16(af[i], bfr[j], acc[i][j], 0, 0, 0);
  }

#pragma unroll
  for (int i = 0; i < 4; ++i) {
    int m_base = wm + i * 16 + quad * 4;
#pragma unroll
    for (int j = 0; j < 2; ++j) {
      int gn = n0 + wn + j * 16 + lr;
#pragma unroll
      for (int r = 0; r < 4; ++r)
        atomicAdd(&out[(size_t)(m_base + r) * 1920 + gn], acc[i][j][r]);
    }
  }
}

// ---------------- Fused RoPE: Q (blocks 0..127) and K in-place (rest) ----------------
__global__ __launch_bounds__(256) void rope_fused(
    bf16* __restrict__ qe, bf16* __restrict__ kbuf,
    const int* __restrict__ pos_ids) {
  if (blockIdx.x < 128) {
    int row = blockIdx.x;
    int b = row >> 6, l = row & 63;
    float pos = (float)pos_ids[b * S_TOT + LV_ + l];
    bf16* qrow = qe + (size_t)row * HD_;
    for (int p = threadIdx.x; p < H_ * 64; p += 256) {
      int hh = p >> 6, i = p & 63;
      float inv_ts = expf(-9.210340371976184f * (float)i * (1.0f / 64.0f));
      float r = pos * inv_ts;
      float sn = sinf(r), cs = cosf(r);
      float x1 = b2f(qrow[hh * DH_ + i]), x2 = b2f(qrow[hh * DH_ + i + 64]);
      qrow[hh * DH_ + i]      = f2b(x1 * cs - x2 * sn);
      qrow[hh * DH_ + i + 64] = f2b(x2 * cs + x1 * sn);
    }
  } else {
    int bid = blockIdx.x - 128;
    int s = bid % S_TOT, b = bid / S_TOT;
    float pos = (float)pos_ids[b * S_TOT + s];
    size_t base = ((size_t)(b * S_TOT + s)) * KVD_;
    for (int t = threadIdx.x; t < KVH_ * 64; t += 256) {
      int kvh = t >> 6, i = t & 63;
      size_t idx = base + kvh * DH_ + i;
      float inv_ts = expf(-9.210340371976184f * (float)i * (1.0f / 64.0f));
      float r = pos * inv_ts;
      float sn = sinf(r), cs = cosf(r);
      float x1 = b2f(kbuf[idx]), x2 = b2f(kbuf[idx + 64]);
      kbuf[idx]      = f2b(x1 * cs - x2 * sn);
      kbuf[idx + 64] = f2b(x2 * cs + x1 * sn);
    }
  }
}

// ---------------- MFMA flash attention, split over keys ----------------
// grid: 576 = (b,h) x 9 splits. Splits 0..7: 128 keys (2 chunks); split 8: 64.
// V pre-transposed [b][kvh][d][s] -> vector staging; strides 80 ushorts.
__global__ __launch_bounds__(256) void attn_part(
    const bf16* __restrict__ qe, const bf16* __restrict__ kbuf,
    const bf16* __restrict__ vbufT,
    float* __restrict__ O_p, float* __restrict__ m_arr,
    float* __restrict__ l_arr) {
  int bh = blockIdx.x & 63;              // (b<<5)|h
  int split = blockIdx.x >> 6;           // 0..8
  int h = bh & 31, b = bh >> 5;
  int kvh = h >> 2;                      // G=4
  int tid = threadIdx.x;
  int lane = tid & 63, wid = tid >> 6;
  int lr = lane & 15, quad = lane >> 4;

  __shared__ ushort Ks[64][152];
  __shared__ ushort vTs[128][80];
  __shared__ ushort sc[4][16][80];

  // Q A-fragments: lane holds Q[m=lr][k=quad*8+j], 4 k-steps of 32
  short8 qf[4];
  {
    const ushort* qptr = (const ushort*)qe +
        ((size_t)(b * LE_ + wid * 16 + lr)) * HD_ + h * DH_ + quad * 8;
#pragma unroll
    for (int ks = 0; ks < 4; ++ks) qf[ks] = *(const short8*)(qptr + ks * 32);
  }

  f32x4 Of[8] = {};                      // O C-frags: row=quad*4+r, col=lr+16*nt
  float m_i[4], l_i[4];
#pragma unroll
  for (int r = 0; r < 4; ++r) { m_i[r] = -1e30f; l_i[r] = 0.f; }

  const float scale = 0.08838834764831845f;   // 128^-0.5
  int nch = (split == 8) ? 1 : 2;
  const ushort* vtb = (const ushort*)vbufT +
      (size_t)(b * KVH_ + kvh) * DH_ * S_TOT;

  for (int c = 0; c < nch; ++c) {
    int key0 = split * 128 + c * 64;
    __syncthreads();
    // ---- stage K chunk (64 keys x 128 d), row-major ----
    {
      int dg = tid & 15, kq = tid >> 4;       // 16 keys per iter
#pragma unroll
      for (int it = 0; it < 4; ++it) {
        int key = it * 16 + kq;
        short8 v = *(const short8*)((const ushort*)kbuf +
            ((size_t)(b * S_TOT + key0 + key) * KVH_ + kvh) * DH_ + dg * 8);
        *(short8*)&Ks[key][dg * 8] = v;
      }
    }
    // ---- stage V chunk from transposed layout: vTs[d][key] (vector copy) ----
    {
      int dd = tid >> 3, kk = (tid & 7) * 8;
#pragma unroll
      for (int it = 0; it < 4; ++it) {
        int d = it * 32 + dd;
        short8 v = *(const short8*)(vtb + (size_t)d * S_TOT + key0 + kk);
        *(short8*)&vTs[d][kk] = v;
      }
    }
    __syncthreads();

    // ---- QK^T: S (16q x 64k) in 4 C-frags ----
    f32x4 Sf[4] = {};
#pragma unroll
    for (int kt = 0; kt < 4; ++kt)
#pragma unroll
      for (int ks = 0; ks < 4; ++ks) {
        short8 kf = *(const short8*)&Ks[kt * 16 + lr][quad * 8 + ks * 32];
        Sf[kt] = __builtin_amdgcn_mfma_f32_16x16x32_bf16(qf[ks], kf, Sf[kt], 0, 0, 0);
      }

    // ---- online softmax (rows r -> q = quad*4+r) ----
#pragma unroll
    for (int kt = 0; kt < 4; ++kt) Sf[kt] *= scale;
#pragma unroll
    for (int r = 0; r < 4; ++r) {
      float mx = fmaxf(fmaxf(Sf[0][r], Sf[1][r]), fmaxf(Sf[2][r], Sf[3][r]));
#pragma unroll
      for (int msk = 1; msk < 16; msk <<= 1) mx = fmaxf(mx, __shfl_xor(mx, msk));
      float mn = fmaxf(m_i[r], mx);
      float alpha = __expf(m_i[r] - mn);
      m_i[r] = mn;
      float ls = 0.f;
#pragma unroll
      for (int kt = 0; kt < 4; ++kt) {
        float p = __expf(Sf[kt][r] - mn);
        Sf[kt][r] = p;
        ls += p;
      }
      l_i[r] = l_i[r] * alpha + ls;
#pragma unroll
      for (int nt = 0; nt < 8; ++nt) Of[nt][r] *= alpha;
#pragma unroll
      for (int kt = 0; kt < 4; ++kt) {
        bf16 t = f2b(Sf[kt][r]);
        sc[wid][quad * 4 + r][kt * 16 + lr] = *(ushort*)&t;
      }
    }

    // ---- PV: O += P (16x64) * V (64x128) ----
#pragma unroll
    for (int ks = 0; ks < 2; ++ks) {
      short8 pf = *(const short8*)&sc[wid][lr][quad * 8 + ks * 32];
#pragma unroll
      for (int nt = 0; nt < 8; ++nt) {
        short8 vf = *(const short8*)&vTs[nt * 16 + lr][quad * 8 + ks * 32];
        Of[nt] = __builtin_amdgcn_mfma_f32_16x16x32_bf16(pf, vf, Of[nt], 0, 0, 0);
      }
    }
  }

  // ---- finalize l: sum across the 16-lane lr group for the true row sum ----
  float l_row[4];
#pragma unroll
  for (int r = 0; r < 4; ++r) {
    float l = l_i[r];
#pragma unroll
    for (int msk = 1; msk < 16; msk <<= 1) l += __shfl_xor(l, msk);
    l_row[r] = l;
  }

  // ---- write partials: O_p[(split*4096 + row)*128 + d], row=(b*32+h)*64+q ----
  size_t rbase = (size_t)split * 4096 + (size_t)bh * 64;
#pragma unroll
  for (int nt = 0; nt < 8; ++nt)
#pragma unroll
    for (int r = 0; r < 4; ++r) {
      int q = wid * 16 + quad * 4 + r;
      O_p[(rbase + q) * 128 + nt * 16 + lr] = Of[nt][r];
    }
  if (lr == 0) {
#pragma unroll
    for (int r = 0; r < 4; ++r) {
      int q = wid * 16 + quad * 4 + r;
      m_arr[rbase + q] = m_i[r];
      l_arr[rbase + q] = l_row[r];
    }
  }
}

// ---------------- Combine attention splits -> ao (bf16), vectorized R8 ----
// Thread handles 4 d's: f32x4 O_p reads (16B/lane), ushort4 ao writes.
__global__ __launch_bounds__(256) void attn_combine(
    const float* __restrict__ O_p, const float* __restrict__ m_arr,
    const float* __restrict__ l_arr, bf16* __restrict__ ao) {
  int t = blockIdx.x * 256 + threadIdx.x;    // over 4096*32
  int d4 = t & 31, row = t >> 5;             // row=(b*32+h)*64+q
  float m_g = -1e30f;
#pragma unroll
  for (int s = 0; s < NSPL; ++s) m_g = fmaxf(m_g, m_arr[s * 4096 + row]);
  float denom = 0.f;
  f32x4 acc = {};
#pragma unroll
  for (int s = 0; s < NSPL; ++s) {
    float w = __expf(m_arr[s * 4096 + row] - m_g);
    denom += w * l_arr[s * 4096 + row];
    f32x4 v = *(const f32x4*)&O_p[((size_t)s * 4096 + row) * 128 + d4 * 4];
    acc += w * v;
  }
  int b = row >> 11, h = (row >> 6) & 31, q = row & 63;
  bf16 h0 = f2b(acc[0] / denom), h1 = f2b(acc[1] / denom);
  bf16 h2 = f2b(acc[2] / denom), h3 = f2b(acc[3] / denom);
  ushort4 o;
  o.x = *(ushort*)&h0; o.y = *(ushort*)&h1; o.z = *(ushort*)&h2; o.w = *(ushort*)&h3;
  *(ushort4*)((ushort*)ao + ((size_t)(b * 64 + q) * 32 + h) * 128 + d4 * 4) = o;
}

extern "C" void kernel_launch(void* const* d_in, const int* in_sizes, int n_in,
                              void* d_out, int out_size, void* d_ws, size_t ws_size,
                              hipStream_t stream) {
  const float* vlm      = (const float*)d_in[0];
  const float* expe     = (const float*)d_in[1];
  const int*   pos      = (const int*)d_in[2];
  // d_in[3] attention_mask: all-True -> unmasked softmax equivalent
  const float* w_ln_vlm = (const float*)d_in[4];
  // d_in[5] Wq_vlm unused (vlm queries don't affect expert outputs)
  const float* Wk_vlm   = (const float*)d_in[6];
  const float* Wv_vlm   = (const float*)d_in[7];
  // d_in[8] Wo_vlm unused
  const float* w_ln_exp = (const float*)d_in[9];
  const float* Wq_exp   = (const float*)d_in[10];
  const float* Wk_exp   = (const float*)d_in[11];
  const float* Wv_exp   = (const float*)d_in[12];
  const float* Wo_exp   = (const float*)d_in[13];
  float* out = (float*)d_out;
  char* ws = (char*)d_ws;

  bf16* hv_b  = (bf16*)(ws + OFF_HVB);
  bf16* WkvT  = (bf16*)(ws + OFF_WKVT);
  bf16* he_b  = (bf16*)(ws + OFF_HEB);
  bf16* WqkvT = (bf16*)(ws + OFF_WQKVT);
  bf16* qe    = (bf16*)(ws + OFF_QE);
  bf16* kbuf  = (bf16*)(ws + OFF_KBUF);
  bf16* vbufT = (bf16*)(ws + OFF_VBUF);
  bf16* ao    = (bf16*)(ws + OFF_AO);
  float* O_p   = (float*)(ws + OFF_OP);
  float* m_arr = (float*)(ws + OFF_M);
  float* l_arr = (float*)(ws + OFF_L);

  // 1) RMSNorm (vlm + expert) -> bf16; expert branch pre-fills out w/ residual
  rmsnorm_both<<<B_ * LV_ + B_ * LE_, 256, 0, stream>>>(
      vlm, w_ln_vlm, hv_b, expe, w_ln_exp, he_b, out);

  // 2) all pre-GEMM weight transpose-converts, one dispatch (vectorized)
  tconv_all<<<4160, 256, 0, stream>>>(Wk_vlm, Wv_vlm, Wq_exp, Wk_exp, Wv_exp,
                                      WkvT, WqkvT);

  // 3) fused GEMM: blocks 0..1023 vlm K/V (64x64 tiles), blocks 1024..1215
  //    expert QKV; K row-major, V transposed, bf16 epilogue
  gemm_fused<<<1216, 256, 0, stream>>>(hv_b, WkvT, he_b, WqkvT, kbuf, vbufT, qe);

  // 4) RoPE (Q + K in-place), one dispatch
  rope_fused<<<128 + B_ * S_TOT, 256, 0, stream>>>(qe, kbuf, pos);

  // 5) flash attention, 9 key-splits -> partials, then combine
  attn_part<<<64 * NSPL, 256, 0, stream>>>(qe, kbuf, vbufT, O_p, m_arr, l_arr);
  attn_combine<<<4096 * 32 / 256, 256, 0, stream>>>(O_p, m_arr, l_arr, ao);

  // 6) output projection, split-K, atomic f32 accumulate into out (+residual)
  gemm_out<<<dim3(30, 16), 256, 0, stream>>>(ao, Wo_exp, out);
}